// Round 7
// baseline (889.868 us; speedup 1.0000x reference)
//
#include <hip/hip_runtime.h>
#include <math.h>

#define BB 64
#define EMB 256
#define N0 1023
#define N1 513
#define NTOK0 (BB * N0)   // 65472
#define NTOK1 (BB * N1)   // 32832
#define GCH 16            // gather chunks per batch

typedef __attribute__((ext_vector_type(8))) short short8;
typedef __attribute__((ext_vector_type(4))) float f32x4;

__device__ __forceinline__ float gelu_f(float x) {
    return 0.5f * x * (1.0f + erff(x * 0.7071067811865476f));
}

__device__ __forceinline__ float4 gelu4(float4 v) {
    return make_float4(gelu_f(v.x), gelu_f(v.y), gelu_f(v.z), gelu_f(v.w));
}

__device__ __forceinline__ float wave_reduce(float v) {
#pragma unroll
    for (int o = 32; o > 0; o >>= 1) v += __shfl_down(v, o, 64);
    return v;
}

// bf16 helpers: pack with round-to-nearest-even; unpack = shift
__device__ __forceinline__ unsigned short f2bf(float f) {
    unsigned int u = __float_as_uint(f);
    u = (u + 0x7FFFu + ((u >> 16) & 1u)) >> 16;
    return (unsigned short)u;
}
__device__ __forceinline__ float bf2f(unsigned short h) {
    return __uint_as_float(((unsigned int)h) << 16);
}

// ---------------- convert weights to bf16 + init imp/counts ----------------
// conv layout per depth d: [branch][fo][k*32+fi]; b39 at 0, b19 at 39936, b9 at 59392.
// bott/mpw: already [d][f][dd] == desired [n][k] B-layout -> direct hi/lo split.
// proj: src [d][k=128][n=256] -> transposed [d][n][k] single bf16.
__global__ void convert_bf16(const float* __restrict__ ew1, const float* __restrict__ ew2,
                             const float* __restrict__ pjw,
                             const float* __restrict__ cw39, const float* __restrict__ cw19,
                             const float* __restrict__ cw9, const float* __restrict__ embw,
                             const float* __restrict__ bott, const float* __restrict__ mpw,
                             unsigned short* __restrict__ w1t, unsigned short* __restrict__ w2t,
                             unsigned short* __restrict__ pjwb,
                             unsigned short* __restrict__ cwh, unsigned short* __restrict__ cwl,
                             unsigned short* __restrict__ ewh, unsigned short* __restrict__ ewl,
                             unsigned short* __restrict__ bth, unsigned short* __restrict__ btl,
                             unsigned short* __restrict__ mph, unsigned short* __restrict__ mpl,
                             float* __restrict__ imp, int* __restrict__ counts) {
    int idx = blockIdx.x * 256 + threadIdx.x;
    if (blockIdx.x == 0 && threadIdx.x >= 252) {
        int i = threadIdx.x - 252;
        imp[i] = 0.0f; counts[i] = 0;
    }
    if (idx < 262144) {
        // out layout [e][n][k]; src [e][k][n]
        int e = idx >> 16, r = idx & 65535, n = r >> 8, k = r & 255;
        w1t[idx] = f2bf(ew1[(e << 16) + (k << 8) + n]);
    } else if (idx < 524288) {
        int j = idx - 262144;
        int e = j >> 16, r = j & 65535, n = r >> 8, k = r & 255;
        w2t[j] = f2bf(ew2[(e << 16) + (k << 8) + n]);
    } else if (idx < 589824) {
        // proj transposed: [d][n][k], src [d][k][n]
        int j = idx - 524288;
        int d = j >> 15, r = j & 32767, n = r >> 7, k = r & 127;
        pjwb[j] = f2bf(pjw[(d << 15) + (k << 8) + n]);
    } else if (idx < 727040) {
        int j = idx - 589824;
        int d = j / 68608, r = j % 68608;
        const float* src; int KT, rr;
        if (r < 39936)      { src = cw39; KT = 39; rr = r; }
        else if (r < 59392) { src = cw19; KT = 19; rr = r - 39936; }
        else                { src = cw9;  KT = 9;  rr = r - 59392; }
        int KK = KT * 32;
        int fo = rr / KK, jj = rr % KK, k = jj >> 5, fi = jj & 31;
        float w = src[(((d * 32 + fo) * 32) + fi) * KT + k];
        unsigned short h = f2bf(w);
        cwh[j] = h;
        cwl[j] = f2bf(w - bf2f(h));
    } else if (idx < 759808) {
        // embw is already [e][k] (k = c*8+s), 256*128
        int j = idx - 727040;
        float w = embw[j];
        unsigned short h = f2bf(w);
        ewh[j] = h;
        ewl[j] = f2bf(w - bf2f(h));
    } else if (idx < 776192) {
        int j = idx - 759808;
        float w = bott[j];
        unsigned short h = f2bf(w);
        bth[j] = h;
        btl[j] = f2bf(w - bf2f(h));
    } else if (idx < 792576) {
        int j = idx - 776192;
        float w = mpw[j];
        unsigned short h = f2bf(w);
        mph[j] = h;
        mpl[j] = f2bf(w - bf2f(h));
    }
}

// ---------------- embedding conv via MFMA: im2col in LDS, hi/lo bf16 ----------------
__global__ __launch_bounds__(256, 2)
void embed_mfma(const float* __restrict__ x, const unsigned short* __restrict__ ewh,
                const unsigned short* __restrict__ ewl, const float* __restrict__ emb_b,
                const float* __restrict__ pos, float* __restrict__ A) {
    int b = blockIdx.y;
    int n0 = blockIdx.x * 64;
    __shared__ __align__(16) unsigned short tokh[64 * 128];  // 16 KB
    __shared__ __align__(16) unsigned short tokl[64 * 128];  // 16 KB
    int tid = threadIdx.x;
#pragma unroll
    for (int it = 0; it < 4; it++) {
        int idx = tid + it * 256;
        int m = idx & 63, c = idx >> 6;
        int tok = n0 + m;
        float v[8] = {0.f, 0.f, 0.f, 0.f, 0.f, 0.f, 0.f, 0.f};
        if (tok < N0) {
            const float* p = x + ((size_t)b * 16 + c) * 4096 + 4 * tok;
            float4 a = *(const float4*)p;
            float4 bq = *(const float4*)(p + 4);
            v[0] = a.x; v[1] = a.y; v[2] = a.z; v[3] = a.w;
            v[4] = bq.x; v[5] = bq.y; v[6] = bq.z; v[7] = bq.w;
        }
        short8 hv, lv;
#pragma unroll
        for (int j = 0; j < 8; j++) {
            unsigned short hh = f2bf(v[j]);
            hv[j] = (short)hh;
            lv[j] = (short)f2bf(v[j] - bf2f(hh));
        }
        int si = (m << 7) + ((c << 3) ^ ((m & 7) << 3));
        *(short8*)(&tokh[si]) = hv;
        *(short8*)(&tokl[si]) = lv;
    }
    __syncthreads();

    int lane = tid & 63, wid = tid >> 6;
    int nb = wid << 6;                 // wave's 64-col emb slice
    int arow = lane & 15;
    int kgrp = (lane >> 4) << 3;
    int rb = (lane >> 4) << 2;

    f32x4 acc[4][4];
#pragma unroll
    for (int mt = 0; mt < 4; mt++)
#pragma unroll
        for (int nt = 0; nt < 4; nt++) acc[mt][nt] = f32x4{0.f, 0.f, 0.f, 0.f};

    for (int ks = 0; ks < 4; ks++) {
        int kk = (ks << 5) + kgrp;
        short8 ah[4], al[4], bh[4], bl[4];
#pragma unroll
        for (int mt = 0; mt < 4; mt++) {
            int m = (mt << 4) + arow;
            int si = (m << 7) + (kk ^ ((m & 7) << 3));
            ah[mt] = *(const short8*)(&tokh[si]);
            al[mt] = *(const short8*)(&tokl[si]);
        }
#pragma unroll
        for (int nt = 0; nt < 4; nt++) {
            int n = nb + (nt << 4) + arow;
            bh[nt] = *(const short8*)(&ewh[(n << 7) + kk]);
            bl[nt] = *(const short8*)(&ewl[(n << 7) + kk]);
        }
#pragma unroll
        for (int mt = 0; mt < 4; mt++) {
#pragma unroll
            for (int nt = 0; nt < 4; nt++) {
                acc[mt][nt] = __builtin_amdgcn_mfma_f32_16x16x32_bf16(ah[mt], bh[nt], acc[mt][nt], 0, 0, 0);
                acc[mt][nt] = __builtin_amdgcn_mfma_f32_16x16x32_bf16(al[mt], bh[nt], acc[mt][nt], 0, 0, 0);
                acc[mt][nt] = __builtin_amdgcn_mfma_f32_16x16x32_bf16(ah[mt], bl[nt], acc[mt][nt], 0, 0, 0);
            }
        }
    }

    float eb[4];
#pragma unroll
    for (int nt = 0; nt < 4; nt++) eb[nt] = emb_b[nb + (nt << 4) + arow];
#pragma unroll
    for (int mt = 0; mt < 4; mt++) {
#pragma unroll
        for (int nt = 0; nt < 4; nt++) {
            int n = nb + (nt << 4) + arow;
#pragma unroll
            for (int r = 0; r < 4; r++) {
                int m = (mt << 4) + rb + r;
                int tok = n0 + m;
                if (tok < N0)
                    A[((size_t)b * N0 + tok) * 256 + n] =
                        acc[mt][nt][r] + eb[nt] + pos[(size_t)tok * 256 + n];
            }
        }
    }
}

// ---------------- wave-per-token: rmsnorm + attn score (+pregelu, +second norm) ------
__global__ void norm_attn_kernel(const float* __restrict__ in, float* __restrict__ outv,
                                 float* __restrict__ score_out, const float* __restrict__ g,
                                 const float* __restrict__ w1, const float* __restrict__ b1,
                                 const float* __restrict__ w2, const float* __restrict__ b2,
                                 int scale_out, int pregelu,
                                 float* __restrict__ outv2, const float* __restrict__ g2,
                                 int T) {
    int wid = threadIdx.x >> 6, lane = threadIdx.x & 63;
    int t = blockIdx.x * 4 + wid;
    if (t >= T) return;
    float4 v = ((const float4*)(in + (size_t)t * 256))[lane];
    if (pregelu) v = gelu4(v);
    float4 xn = v;
    if (g != nullptr) {
        float ss = v.x * v.x + v.y * v.y + v.z * v.z + v.w * v.w;
        ss = wave_reduce(ss);
        ss = __shfl(ss, 0, 64);
        float inv = 16.0f / fmaxf(sqrtf(ss), 1e-12f);
        float4 g4 = ((const float4*)g)[lane];
        xn.x = v.x * inv * g4.x; xn.y = v.y * inv * g4.y;
        xn.z = v.z * inv * g4.z; xn.w = v.w * inv * g4.w;
    }
    float p[8];
#pragma unroll
    for (int j = 0; j < 8; j++) p[j] = 0.0f;
    const float xv[4] = {xn.x, xn.y, xn.z, xn.w};
#pragma unroll
    for (int c = 0; c < 4; c++) {
        const float4* wr = (const float4*)(w1 + (4 * lane + c) * 8);
        float4 wa = wr[0], wb = wr[1];
        float xx = xv[c];
        p[0] += xx * wa.x; p[1] += xx * wa.y; p[2] += xx * wa.z; p[3] += xx * wa.w;
        p[4] += xx * wb.x; p[5] += xx * wb.y; p[6] += xx * wb.z; p[7] += xx * wb.w;
    }
#pragma unroll
    for (int j = 0; j < 8; j++) p[j] = wave_reduce(p[j]);
    float sc = 0.0f;
    if (lane == 0) {
        float z = b2[0];
#pragma unroll
        for (int j = 0; j < 8; j++) z += tanhf(p[j] + b1[j]) * w2[j];
        sc = 1.0f / (1.0f + expf(-z));
        if (score_out) score_out[t] = sc;
    }
    sc = __shfl(sc, 0, 64);
    if (outv) {
        float m = scale_out ? sc : 1.0f;
        float4 o = make_float4(xn.x * m, xn.y * m, xn.z * m, xn.w * m);
        ((float4*)(outv + (size_t)t * 256))[lane] = o;
    }
    if (outv2) {
        float ss2 = xn.x * xn.x + xn.y * xn.y + xn.z * xn.z + xn.w * xn.w;
        ss2 = wave_reduce(ss2);
        ss2 = __shfl(ss2, 0, 64);
        float inv2 = 16.0f / fmaxf(sqrtf(ss2), 1e-12f);
        float4 q4 = ((const float4*)g2)[lane];
        float4 o;
        o.x = xn.x * inv2 * q4.x; o.y = xn.y * inv2 * q4.y;
        o.z = xn.z * inv2 * q4.z; o.w = xn.w * inv2 * q4.w;
        ((float4*)(outv2 + (size_t)t * 256))[lane] = o;
    }
}

// ---------------- wave-per-token rmsnorm ----------------
__global__ void rmsnorm_kernel(const float* __restrict__ in, float* __restrict__ out,
                               const float* __restrict__ g, int T) {
    int wid = threadIdx.x >> 6, lane = threadIdx.x & 63;
    int t = blockIdx.x * 4 + wid;
    if (t >= T) return;
    float4 v = ((const float4*)(in + (size_t)t * 256))[lane];
    float ss = v.x * v.x + v.y * v.y + v.z * v.z + v.w * v.w;
    ss = wave_reduce(ss);
    ss = __shfl(ss, 0, 64);
    float inv = 16.0f / fmaxf(sqrtf(ss), 1e-12f);
    float4 g4 = ((const float4*)g)[lane];
    float4 o;
    o.x = v.x * inv * g4.x; o.y = v.y * inv * g4.y;
    o.z = v.z * inv * g4.z; o.w = v.w * inv * g4.w;
    ((float4*)(out + (size_t)t * 256))[lane] = o;
}

// ---------------- pointwise bottleneck + maxpool via MFMA, hi/lo bf16 ----------------
__global__ __launch_bounds__(256, 2)
void pw_mfma(const float* __restrict__ xn, const unsigned short* __restrict__ bwh,
             const unsigned short* __restrict__ bwl, const unsigned short* __restrict__ mwh,
             const unsigned short* __restrict__ mwl, const float* __restrict__ bng,
             const float* __restrict__ bnb, float* __restrict__ xb,
             float* __restrict__ cat, int N) {
    int b = blockIdx.y;
    int t0 = blockIdx.x * 32;
    __shared__ __align__(16) unsigned short xth[34 * 256];
    __shared__ __align__(16) unsigned short xtl[34 * 256];
    __shared__ __align__(16) unsigned short xmh[32 * 256];
    __shared__ __align__(16) unsigned short xml[32 * 256];
    const float* xbase = xn + (size_t)b * N * 256;
    int tid = threadIdx.x;
    // stage xt rows (tokens t0-1 .. t0+32), hi/lo, swizzled; OOB = -inf (hi), 0 (lo)
    for (int idx = tid; idx < 34 * 32; idx += 256) {
        int r = idx >> 5, p = (idx & 31) << 3;
        int t = t0 - 1 + r;
        short8 hv, lv;
        if (t >= 0 && t < N) {
            const float4* q = (const float4*)(xbase + (size_t)t * 256 + p);
            float4 a = q[0], c = q[1];
            float v[8] = {a.x, a.y, a.z, a.w, c.x, c.y, c.z, c.w};
#pragma unroll
            for (int j = 0; j < 8; j++) {
                unsigned short hh = f2bf(v[j]);
                hv[j] = (short)hh;
                lv[j] = (short)f2bf(v[j] - bf2f(hh));
            }
        } else {
#pragma unroll
            for (int j = 0; j < 8; j++) { hv[j] = (short)0xFF80; lv[j] = 0; }
        }
        int si = (r << 8) + (p ^ ((r & 7) << 3));
        *(short8*)(&xth[si]) = hv;
        *(short8*)(&xtl[si]) = lv;
    }
    __syncthreads();
    // xm[r] = rowwise max of xt rows r, r+1, r+2 (tokens t-1, t, t+1)
    for (int idx = tid; idx < 32 * 32; idx += 256) {
        int r = idx >> 5, p = (idx & 31) << 3;
        int s0 = ((r + 0) << 8) + (p ^ (((r + 0) & 7) << 3));
        int s1 = ((r + 1) << 8) + (p ^ (((r + 1) & 7) << 3));
        int s2 = ((r + 2) << 8) + (p ^ (((r + 2) & 7) << 3));
        short8 h0 = *(const short8*)(&xth[s0]), l0 = *(const short8*)(&xtl[s0]);
        short8 h1 = *(const short8*)(&xth[s1]), l1 = *(const short8*)(&xtl[s1]);
        short8 h2 = *(const short8*)(&xth[s2]), l2 = *(const short8*)(&xtl[s2]);
        short8 hv, lv;
#pragma unroll
        for (int j = 0; j < 8; j++) {
            float a = bf2f((unsigned short)h0[j]) + bf2f((unsigned short)l0[j]);
            float c = bf2f((unsigned short)h1[j]) + bf2f((unsigned short)l1[j]);
            float d = bf2f((unsigned short)h2[j]) + bf2f((unsigned short)l2[j]);
            float m = fmaxf(fmaxf(a, c), d);
            unsigned short hh = f2bf(m);
            hv[j] = (short)hh;
            lv[j] = (short)f2bf(m - bf2f(hh));
        }
        int si = (r << 8) + (p ^ ((r & 7) << 3));
        *(short8*)(&xmh[si]) = hv;
        *(short8*)(&xml[si]) = lv;
    }
    __syncthreads();

    int lane = tid & 63, wid = tid >> 6;
    int mt = wid & 1, path = wid >> 1;   // path 0 = bottleneck, 1 = maxpool
    int arow = lane & 15, kgrp = (lane >> 4) << 3, rb = (lane >> 4) << 2;
    const unsigned short* Wh = path ? mwh : bwh;
    const unsigned short* Wl = path ? mwl : bwl;
    f32x4 acc[2];
    acc[0] = f32x4{0.f, 0.f, 0.f, 0.f};
    acc[1] = f32x4{0.f, 0.f, 0.f, 0.f};

    int m = (mt << 4) + arow;
    int rowA = path ? m : (m + 1);   // bott reads xt row m+1 (token t0+m); mp reads xm row m
    const unsigned short* Ah = path ? xmh : xth;
    const unsigned short* Al = path ? xml : xtl;
    for (int ks = 0; ks < 8; ks++) {
        int kk = (ks << 5) + kgrp;
        int si = (rowA << 8) + (kk ^ ((rowA & 7) << 3));
        short8 ah = *(const short8*)(&Ah[si]);
        short8 al = *(const short8*)(&Al[si]);
#pragma unroll
        for (int nt = 0; nt < 2; nt++) {
            int n = (nt << 4) + arow;
            short8 bh = *(const short8*)(&Wh[n * 256 + kk]);
            short8 bl = *(const short8*)(&Wl[n * 256 + kk]);
            acc[nt] = __builtin_amdgcn_mfma_f32_16x16x32_bf16(ah, bh, acc[nt], 0, 0, 0);
            acc[nt] = __builtin_amdgcn_mfma_f32_16x16x32_bf16(al, bh, acc[nt], 0, 0, 0);
            acc[nt] = __builtin_amdgcn_mfma_f32_16x16x32_bf16(ah, bl, acc[nt], 0, 0, 0);
        }
    }

    const float BN_DIV = 1.0000050f;
    if (path == 0) {
#pragma unroll
        for (int nt = 0; nt < 2; nt++) {
            int n = (nt << 4) + arow;
#pragma unroll
            for (int r = 0; r < 4; r++) {
                int t = t0 + (mt << 4) + rb + r;
                if (t < N) xb[((size_t)b * N + t) * 32 + n] = acc[nt][r];
            }
        }
    } else {
#pragma unroll
        for (int nt = 0; nt < 2; nt++) {
            int n = (nt << 4) + arow;
            float scl = bng[96 + n] / BN_DIV;
            float sh = bnb[96 + n];
#pragma unroll
            for (int r = 0; r < 4; r++) {
                int t = t0 + (mt << 4) + rb + r;
                if (t < N)
                    cat[((size_t)b * N + t) * 128 + 96 + n] = gelu_f(acc[nt][r] * scl + sh);
            }
        }
    }
}

// ---------------- inception time-convs via MFMA, split hi/lo bf16 ----------------
// Block: 128 output tokens (4 waves x 2 m-tiles x 16), all 3 branches, 32 fo each.
// LDS: 167 rows (128 + 39-tap halo, P=19 left pad) x 32 ch, row stride 32 shorts,
// FFN-style slot swizzle: si = r*32 + ((slot ^ ((r>>1)&3))<<3) + sub  (slot=c>>3).
// Weight loads per k serve BOTH m-tiles -> halves L2 weight traffic vs 64-tok tile.
__global__ __launch_bounds__(256, 2)
void conv_mfma(const float* __restrict__ xb, const unsigned short* __restrict__ wh,
               const unsigned short* __restrict__ wl, const float* __restrict__ bng,
               const float* __restrict__ bnb, float* __restrict__ cat, int N) {
    int b = blockIdx.y;
    int t0 = blockIdx.x * 128;
    __shared__ __align__(16) unsigned short tokh[167 * 32];
    __shared__ __align__(16) unsigned short tokl[167 * 32];
    const float* xbase = xb + (size_t)b * N * 32;
    int tid = threadIdx.x;
    for (int idx = tid; idx < 167 * 16; idx += 256) {
        int r = idx >> 4, c = (idx & 15) << 1;
        int t = t0 - 19 + r;
        float vx = 0.f, vy = 0.f;
        if (t >= 0 && t < N) {
            const float2 v = *(const float2*)(xbase + (size_t)t * 32 + c);
            vx = v.x; vy = v.y;
        }
        unsigned short h0 = f2bf(vx), h1 = f2bf(vy);
        unsigned short l0 = f2bf(vx - bf2f(h0)), l1 = f2bf(vy - bf2f(h1));
        int si = (r << 5) + ((((c >> 3) ^ ((r >> 1) & 3)) << 3) | (c & 7));
        *(unsigned int*)(&tokh[si]) = (unsigned)h0 | ((unsigned)h1 << 16);
        *(unsigned int*)(&tokl[si]) = (unsigned)l0 | ((unsigned)l1 << 16);
    }
    __syncthreads();
    int lane = tid & 63, wid = tid >> 6;
    int arow = lane & 15, g = lane >> 4, kgrp = g << 3;
    int rb = g << 2;
    f32x4 acc[3][2][2];
#pragma unroll
    for (int i = 0; i < 3; i++)
#pragma unroll
        for (int m = 0; m < 2; m++) {
            acc[i][m][0] = f32x4{0.f, 0.f, 0.f, 0.f};
            acc[i][m][1] = f32x4{0.f, 0.f, 0.f, 0.f};
        }

#define SIA(row) (((row) << 5) + ((g ^ (((row) >> 1) & 3)) << 3))
#define CONV_BR(KT, BOFF, WOFF, BR)                                                        \
    {                                                                                      \
        const int KK = (KT) * 32;                                                          \
        int r0 = (WOFF) + wid * 32 + arow;                                                 \
        const unsigned short* whp = wh + (BOFF) + arow * KK + kgrp;                        \
        const unsigned short* wlp = wl + (BOFF) + arow * KK + kgrp;                        \
        for (int k = 0; k < (KT); k++) {                                                   \
            int ra = r0 + k, rc = r0 + 16 + k;                                             \
            short8 ah0 = *(const short8*)(&tokh[SIA(ra)]);                                 \
            short8 al0 = *(const short8*)(&tokl[SIA(ra)]);                                 \
            short8 ah1 = *(const short8*)(&tokh[SIA(rc)]);                                 \
            short8 al1 = *(const short8*)(&tokl[SIA(rc)]);                                 \
            short8 bh0 = *(const short8*)(&whp[k * 32]);                                   \
            short8 bl0 = *(const short8*)(&wlp[k * 32]);                                   \
            short8 bh1 = *(const short8*)(&whp[16 * KK + k * 32]);                         \
            short8 bl1 = *(const short8*)(&wlp[16 * KK + k * 32]);                         \
            acc[BR][0][0] = __builtin_amdgcn_mfma_f32_16x16x32_bf16(ah0, bh0, acc[BR][0][0], 0, 0, 0); \
            acc[BR][0][1] = __builtin_amdgcn_mfma_f32_16x16x32_bf16(ah0, bh1, acc[BR][0][1], 0, 0, 0); \
            acc[BR][0][0] = __builtin_amdgcn_mfma_f32_16x16x32_bf16(al0, bh0, acc[BR][0][0], 0, 0, 0); \
            acc[BR][0][1] = __builtin_amdgcn_mfma_f32_16x16x32_bf16(al0, bh1, acc[BR][0][1], 0, 0, 0); \
            acc[BR][0][0] = __builtin_amdgcn_mfma_f32_16x16x32_bf16(ah0, bl0, acc[BR][0][0], 0, 0, 0); \
            acc[BR][0][1] = __builtin_amdgcn_mfma_f32_16x16x32_bf16(ah0, bl1, acc[BR][0][1], 0, 0, 0); \
            acc[BR][1][0] = __builtin_amdgcn_mfma_f32_16x16x32_bf16(ah1, bh0, acc[BR][1][0], 0, 0, 0); \
            acc[BR][1][1] = __builtin_amdgcn_mfma_f32_16x16x32_bf16(ah1, bh1, acc[BR][1][1], 0, 0, 0); \
            acc[BR][1][0] = __builtin_amdgcn_mfma_f32_16x16x32_bf16(al1, bh0, acc[BR][1][0], 0, 0, 0); \
            acc[BR][1][1] = __builtin_amdgcn_mfma_f32_16x16x32_bf16(al1, bh1, acc[BR][1][1], 0, 0, 0); \
            acc[BR][1][0] = __builtin_amdgcn_mfma_f32_16x16x32_bf16(ah1, bl0, acc[BR][1][0], 0, 0, 0); \
            acc[BR][1][1] = __builtin_amdgcn_mfma_f32_16x16x32_bf16(ah1, bl1, acc[BR][1][1], 0, 0, 0); \
        }                                                                                  \
    }

    CONV_BR(39, 0, 0, 0)
    CONV_BR(19, 39936, 10, 1)
    CONV_BR(9, 59392, 15, 2)
#undef CONV_BR
#undef SIA

    const float BN_DIV = 1.0000050f;
    const int COFFS[3] = {0, 32, 64};
#pragma unroll
    for (int br = 0; br < 3; br++) {
#pragma unroll
        for (int mt = 0; mt < 2; mt++) {
#pragma unroll
            for (int nt = 0; nt < 2; nt++) {
                int fo = COFFS[br] + nt * 16 + arow;
                float scl = bng[fo] / BN_DIV;
                float sh = bnb[fo];
#pragma unroll
                for (int r = 0; r < 4; r++) {
                    int t = t0 + wid * 32 + mt * 16 + rb + r;
                    if (t < N)
                        cat[((size_t)b * N + t) * 128 + fo] =
                            gelu_f(acc[br][mt][nt][r] * scl + sh);
                }
            }
        }
    }
}

// ---------------- proj via MFMA: K=128, hi/lo bf16 activations, bf16 weights ----------
// Block: 64 tokens, 4 waves x 64-col N-slice. A[t*256+n] += acc + bias.
__global__ __launch_bounds__(256, 2)
void proj_mfma(const float* __restrict__ cat, const unsigned short* __restrict__ pjt,
               const float* __restrict__ pb, float* __restrict__ A, int TN) {
    int t0 = blockIdx.x * 64;
    __shared__ __align__(16) unsigned short tokh[64 * 128];  // 16 KB
    __shared__ __align__(16) unsigned short tokl[64 * 128];  // 16 KB
    int tid = threadIdx.x;
#pragma unroll
    for (int it = 0; it < 4; it++) {
        int idx = tid + it * 256;
        int m = idx >> 4, c = idx & 15;
        int t = t0 + m;
        float v[8] = {0.f, 0.f, 0.f, 0.f, 0.f, 0.f, 0.f, 0.f};
        if (t < TN) {
            const float4* q = (const float4*)(cat + (size_t)t * 128 + (c << 3));
            float4 a = q[0], bq = q[1];
            v[0] = a.x; v[1] = a.y; v[2] = a.z; v[3] = a.w;
            v[4] = bq.x; v[5] = bq.y; v[6] = bq.z; v[7] = bq.w;
        }
        short8 hv, lv;
#pragma unroll
        for (int j = 0; j < 8; j++) {
            unsigned short hh = f2bf(v[j]);
            hv[j] = (short)hh;
            lv[j] = (short)f2bf(v[j] - bf2f(hh));
        }
        int si = (m << 7) + ((c << 3) ^ ((m & 7) << 3));
        *(short8*)(&tokh[si]) = hv;
        *(short8*)(&tokl[si]) = lv;
    }
    __syncthreads();

    int lane = tid & 63, wid = tid >> 6;
    int nb = wid << 6;
    int arow = lane & 15;
    int kgrp = (lane >> 4) << 3;
    int rb = (lane >> 4) << 2;

    f32x4 acc[4][4];
#pragma unroll
    for (int mt = 0; mt < 4; mt++)
#pragma unroll
        for (int nt = 0; nt < 4; nt++) acc[mt][nt] = f32x4{0.f, 0.f, 0.f, 0.f};

    for (int ks = 0; ks < 4; ks++) {
        int kk = (ks << 5) + kgrp;
        short8 ah[4], al[4], bw[4];
#pragma unroll
        for (int mt = 0; mt < 4; mt++) {
            int m = (mt << 4) + arow;
            int si = (m << 7) + (kk ^ ((m & 7) << 3));
            ah[mt] = *(const short8*)(&tokh[si]);
            al[mt] = *(const short8*)(&tokl[si]);
        }
#pragma unroll
        for (int nt = 0; nt < 4; nt++) {
            int n = nb + (nt << 4) + arow;
            bw[nt] = *(const short8*)(&pjt[(n << 7) + kk]);
        }
#pragma unroll
        for (int mt = 0; mt < 4; mt++) {
#pragma unroll
            for (int nt = 0; nt < 4; nt++) {
                acc[mt][nt] = __builtin_amdgcn_mfma_f32_16x16x32_bf16(ah[mt], bw[nt], acc[mt][nt], 0, 0, 0);
                acc[mt][nt] = __builtin_amdgcn_mfma_f32_16x16x32_bf16(al[mt], bw[nt], acc[mt][nt], 0, 0, 0);
            }
        }
    }

    float bias[4];
#pragma unroll
    for (int nt = 0; nt < 4; nt++) bias[nt] = pb[nb + (nt << 4) + arow];
#pragma unroll
    for (int mt = 0; mt < 4; mt++) {
#pragma unroll
        for (int nt = 0; nt < 4; nt++) {
            int n = nb + (nt << 4) + arow;
#pragma unroll
            for (int r = 0; r < 4; r++) {
                int t = t0 + (mt << 4) + rb + r;
                if (t < TN) {
                    float* ap = A + (size_t)t * 256 + n;
                    *ap += acc[mt][nt][r] + bias[nt];
                }
            }
        }
    }
}

// ---------------- top-512-of-1023 per batch ----------------
__global__ __launch_bounds__(1024) void topk_kernel(const float* __restrict__ s,
                                                    int* __restrict__ selpos) {
    int b = blockIdx.x;
    int tid = threadIdx.x;
    __shared__ float srt[1024];
    __shared__ int buf[1024];
    __shared__ int Gtot_s;
    float val = (tid < N0) ? s[(size_t)b * N0 + tid] : -INFINITY;
    srt[tid] = val;
    __syncthreads();
    for (int ksz = 2; ksz <= 1024; ksz <<= 1) {
        for (int j = ksz >> 1; j > 0; j >>= 1) {
            int ixj = tid ^ j;
            if (ixj > tid) {
                float a = srt[tid], c = srt[ixj];
                bool up = ((tid & ksz) == 0);
                if ((a > c) == up) { srt[tid] = c; srt[ixj] = a; }
            }
            __syncthreads();
        }
    }
    float thr = srt[512];
    __syncthreads();
    int isG = (val > thr) ? 1 : 0;
    int isE = (val == thr) ? 1 : 0;
    buf[tid] = isG;
    __syncthreads();
    for (int off = 1; off < 1024; off <<= 1) {
        int cur = buf[tid];
        int add = (tid >= off) ? buf[tid - off] : 0;
        __syncthreads();
        buf[tid] = cur + add;
        __syncthreads();
    }
    if (tid == 0) Gtot_s = buf[1023];
    __syncthreads();
    int Gtot = Gtot_s;
    int Eneed = 512 - Gtot;
    buf[tid] = isE;
    __syncthreads();
    for (int off = 1; off < 1024; off <<= 1) {
        int cur = buf[tid];
        int add = (tid >= off) ? buf[tid - off] : 0;
        __syncthreads();
        buf[tid] = cur + add;
        __syncthreads();
    }
    int eqExcl = buf[tid] - isE;
    int sel = (isG || (isE && eqExcl < Eneed)) ? 1 : 0;
    __syncthreads();
    buf[tid] = sel;
    __syncthreads();
    for (int off = 1; off < 1024; off <<= 1) {
        int cur = buf[tid];
        int add = (tid >= off) ? buf[tid - off] : 0;
        __syncthreads();
        buf[tid] = cur + add;
        __syncthreads();
    }
    int pos = buf[tid] - sel;
    selpos[b * 1024 + tid] = sel ? pos : -1;
}

// ---------------- scatter: 4 token-groups x float4; 4 partials per chunk ----------------
__global__ void scatter_kernel(const float* __restrict__ xn, const float* __restrict__ s,
                               const int* __restrict__ selpos, float* __restrict__ A,
                               float* __restrict__ part) {
    int b = blockIdx.y;
    int chunk = blockIdx.x;
    int wid = threadIdx.x >> 6, lane = threadIdx.x & 63;
    int t0 = chunk * 64;
    __shared__ float sl[64];
    __shared__ int pl[64];
    if (threadIdx.x < 64) {
        int t = t0 + threadIdx.x;
        sl[threadIdx.x] = (t < N0) ? s[(size_t)b * N0 + t] : 0.0f;
        pl[threadIdx.x] = (t < N0) ? selpos[b * 1024 + t] : -1;
    }
    __syncthreads();
    const float* xbase = xn + ((size_t)b * N0 + t0) * 256;
    float* obase = A + (size_t)b * N1 * 256;
    float4 nonsel = make_float4(0.f, 0.f, 0.f, 0.f);
    int tmax = (t0 + 64 <= N0) ? 64 : (N0 - t0);
    for (int i = wid; i < tmax; i += 4) {
        float sc = sl[i];
        float4 v = ((const float4*)(xbase + (size_t)i * 256))[lane];
        v.x *= sc; v.y *= sc; v.z *= sc; v.w *= sc;
        int p = pl[i];
        if (p >= 0) ((float4*)(obase + (size_t)p * 256))[lane] = v;
        else { nonsel.x += v.x; nonsel.y += v.y; nonsel.z += v.z; nonsel.w += v.w; }
    }
    ((float4*)(part + ((size_t)(b * GCH + chunk) * 4 + wid) * 256))[lane] = nonsel;
}

// ---------------- reduce chunk partials (64 per batch) -> extra row ----------------
__global__ void extra_kernel(const float* __restrict__ part, float* __restrict__ A) {
    int b = blockIdx.x, d = threadIdx.x;
    float acc = 0.0f;
    for (int c = 0; c < GCH * 4; c++) acc += part[((size_t)b * GCH * 4 + c) * 256 + d];
    A[((size_t)b * N1 + 512) * 256 + d] = acc;
}

// ---------------- gate: one token per thread, block-aggregated routing ----------------
__global__ void gate_kernel(const float* __restrict__ xn2, const float* __restrict__ gw,
                            const float* __restrict__ gb, float* __restrict__ topval,
                            int* __restrict__ buckets, int* __restrict__ counts,
                            float* __restrict__ imp, int T) {
    int tid = threadIdx.x;
    int t = blockIdx.x * 256 + tid;
    __shared__ float4 gws[256];
    __shared__ int lcount[4];
    __shared__ int lbase[4];
    __shared__ float limp[4];
    gws[tid] = ((const float4*)gw)[tid];
    if (tid < 4) { lcount[tid] = 0; limp[tid] = 0.0f; }
    __syncthreads();
    bool valid = (t < T);
    float a0 = 0, a1 = 0, a2 = 0, a3 = 0;
    if (valid) {
        const float4* xb4 = (const float4*)(xn2 + (size_t)t * 256);
#pragma unroll 8
        for (int d4 = 0; d4 < 64; d4++) {
            float4 xv = xb4[d4];
            float4 w0 = gws[4 * d4], w1 = gws[4 * d4 + 1];
            float4 w2 = gws[4 * d4 + 2], w3 = gws[4 * d4 + 3];
            a0 += xv.x * w0.x + xv.y * w1.x + xv.z * w2.x + xv.w * w3.x;
            a1 += xv.x * w0.y + xv.y * w1.y + xv.z * w2.y + xv.w * w3.y;
            a2 += xv.x * w0.z + xv.y * w1.z + xv.z * w2.z + xv.w * w3.z;
            a3 += xv.x * w0.w + xv.y * w1.w + xv.z * w2.w + xv.w * w3.w;
        }
    }
    float q0 = 0, q1 = 0, q2 = 0, q3 = 0;
    int eid = 0;
    int lrank = 0;
    if (valid) {
        float l0 = a0 + gb[0], l1 = a1 + gb[1], l2 = a2 + gb[2], l3 = a3 + gb[3];
        float m = fmaxf(fmaxf(l0, l1), fmaxf(l2, l3));
        float e0 = expf(l0 - m), e1 = expf(l1 - m), e2 = expf(l2 - m), e3 = expf(l3 - m);
        float ssum = e0 + e1 + e2 + e3;
        q0 = e0 / ssum; q1 = e1 / ssum; q2 = e2 / ssum; q3 = e3 / ssum;
        float bv = q0;
        if (q1 > bv) { bv = q1; eid = 1; }
        if (q2 > bv) { bv = q2; eid = 2; }
        if (q3 > bv) { bv = q3; eid = 3; }
        topval[t] = bv;
        lrank = atomicAdd(&lcount[eid], 1);
    }
    float r0 = wave_reduce(q0), r1 = wave_reduce(q1);
    float r2 = wave_reduce(q2), r3 = wave_reduce(q3);
    if ((tid & 63) == 0) {
        atomicAdd(&limp[0], r0); atomicAdd(&limp[1], r1);
        atomicAdd(&limp[2], r2); atomicAdd(&limp[3], r3);
    }
    __syncthreads();
    if (tid < 4) {
        lbase[tid] = atomicAdd(&counts[tid], lcount[tid]);
        atomicAdd(&imp[tid], limp[tid]);
    }
    __syncthreads();
    if (valid) buckets[eid * T + lbase[eid] + lrank] = t;
}

// ---------------- expert FFN: MFMA bf16, split hi/lo activations ----------------
#define FFN_KLOOP(WPTR)                                                                    \
    for (int ks = 0; ks < 8; ks++) {                                                       \
        int kk = (ks << 5) + kgrp;                                                         \
        short8 ah[4], al[4], bw[4];                                                        \
        _Pragma("unroll")                                                                  \
        for (int mt = 0; mt < 4; mt++) {                                                   \
            int m = (mt << 4) + arow;                                                      \
            int si = (m << 8) + (kk ^ ((m & 7) << 3));                                     \
            ah[mt] = *(const short8*)(&tokh[si]);                                          \
            al[mt] = *(const short8*)(&tokl[si]);                                          \
        }                                                                                  \
        _Pragma("unroll")                                                                  \
        for (int nt = 0; nt < 4; nt++)                                                     \
            bw[nt] = *(const short8*)(&WPTR[((size_t)(nb + (nt << 4) + arow) << 8) + kk]); \
        _Pragma("unroll")                                                                  \
        for (int mt = 0; mt < 4; mt++) {                                                   \
            _Pragma("unroll")                                                              \
            for (int nt = 0; nt < 4; nt++) {                                               \
                acc[mt][nt] = __builtin_amdgcn_mfma_f32_16x16x32_bf16(                     \
                    ah[mt], bw[nt], acc[mt][nt], 0, 0, 0);                                 \
                acc[mt][nt] = __builtin_amdgcn_mfma_f32_16x16x32_bf16(                     \
                    al[mt], bw[nt], acc[mt][nt], 0, 0, 0);                                 \
            }                                                                              \
        }                                                                                  \
    }

__global__ __launch_bounds__(256, 2)
void ffn_kernel(const float* __restrict__ xn2, const unsigned short* __restrict__ w1t,
                const float* __restrict__ b1, const unsigned short* __restrict__ w2t,
                const float* __restrict__ b2, const float* __restrict__ topval,
                const int* __restrict__ buckets, const int* __restrict__ counts,
                float* __restrict__ C, int T) {
    int e = blockIdx.y;
    int cnt = counts[e];
    int base = blockIdx.x * 64;
    if (base >= cnt) return;
    __shared__ __align__(16) unsigned short tokh[64 * 256];  // 32 KB
    __shared__ __align__(16) unsigned short tokl[64 * 256];  // 32 KB
    __shared__ int tids[64];
    __shared__ float tv[64];
    int tid = threadIdx.x;
    if (tid < 64) {
        int idx = base + tid;
        int t = (idx < cnt) ? buckets[e * T + idx] : -1;
        tids[tid] = t;
        tv[tid] = (t >= 0) ? topval[t] : 0.0f;
    }
    __syncthreads();
#pragma unroll
    for (int it = 0; it < 8; it++) {
        int cc = tid + it * 256;
        int m = cc >> 5, d0 = (cc & 31) << 3;
        int t = tids[m];
        float4 a = make_float4(0.f, 0.f, 0.f, 0.f), b = a;
        if (t >= 0) {
            const float4* p = (const float4*)(xn2 + (size_t)t * 256 + d0);
            a = p[0]; b = p[1];
        }
        float v[8] = {a.x, a.y, a.z, a.w, b.x, b.y, b.z, b.w};
        short8 hv, lv;
#pragma unroll
        for (int j = 0; j < 8; j++) {
            unsigned short hh = f2bf(v[j]);
            hv[j] = (short)hh;
            lv[j] = (short)f2bf(v[j] - bf2f(hh));
        }
        int si = (m << 8) + (d0 ^ ((m & 7) << 3));
        *(short8*)(&tokh[si]) = hv;
        *(short8*)(&tokl[si]) = lv;
    }
    __syncthreads();

    int lane = tid & 63, wid = tid >> 6;
    int nb = wid << 6;
    int arow = lane & 15;
    int kgrp = (lane >> 4) << 3;
    int rb = (lane >> 4) << 2;
    const unsigned short* W1 = w1t + ((size_t)e << 16);
    const unsigned short* W2 = w2t + ((size_t)e << 16);

    f32x4 acc[4][4];
#pragma unroll
    for (int mt = 0; mt < 4; mt++)
#pragma unroll
        for (int nt = 0; nt < 4; nt++) acc[mt][nt] = f32x4{0.f, 0.f, 0.f, 0.f};

    // ---- layer 1 ----
    FFN_KLOOP(W1)

    float b1v[4];
#pragma unroll
    for (int nt = 0; nt < 4; nt++) b1v[nt] = b1[(e << 8) + nb + (nt << 4) + arow];
    __syncthreads();
#pragma unroll
    for (int mt = 0; mt < 4; mt++) {
#pragma unroll
        for (int nt = 0; nt < 4; nt++) {
            int kd = nb + (nt << 4) + arow;
#pragma unroll
            for (int r = 0; r < 4; r++) {
                int m = (mt << 4) + rb + r;
                float mid = gelu_f(acc[mt][nt][r] + b1v[nt]);
                unsigned short hh = f2bf(mid);
                int si = (m << 8) + (kd ^ ((m & 7) << 3));
                tokh[si] = hh;
                tokl[si] = f2bf(mid - bf2f(hh));
            }
        }
    }
    __syncthreads();

#pragma unroll
    for (int mt = 0; mt < 4; mt++)
#pragma unroll
        for (int nt = 0; nt < 4; nt++) acc[mt][nt] = f32x4{0.f, 0.f, 0.f, 0.f};

    // ---- layer 2 ----
    FFN_KLOOP(W2)

    float b2v[4];
#pragma unroll
    for (int nt = 0; nt < 4; nt++) b2v[nt] = b2[(e << 8) + nb + (nt << 4) + arow];
#pragma unroll
    for (int mt = 0; mt < 4; mt++) {
        int tt[4]; float tvv[4];
#pragma unroll
        for (int r = 0; r < 4; r++) {
            int m = (mt << 4) + rb + r;
            tt[r] = tids[m];
            tvv[r] = tv[m];
        }
#pragma unroll
        for (int nt = 0; nt < 4; nt++) {
            int n = nb + (nt << 4) + arow;
#pragma unroll
            for (int r = 0; r < 4; r++) {
                int t = tt[r];
                if (t >= 0) {
                    float val = acc[mt][nt][r] + b2v[nt];
                    C[(size_t)t * 256 + n] =
                        xn2[(size_t)t * 256 + n] + val * tvv[r];
                }
            }
        }
    }
}

// ---------------- wave-per-token: A += gelu(rmsnorm(C, moe_gamma)) ----------------
__global__ void moe_add_kernel(const float* __restrict__ C, float* __restrict__ A,
                               const float* __restrict__ gamma, int T) {
    int wid = threadIdx.x >> 6, lane = threadIdx.x & 63;
    int t = blockIdx.x * 4 + wid;
    if (t >= T) return;
    float4 v = ((const float4*)(C + (size_t)t * 256))[lane];
    float ss = v.x * v.x + v.y * v.y + v.z * v.z + v.w * v.w;
    ss = wave_reduce(ss);
    ss = __shfl(ss, 0, 64);
    float inv = 16.0f / fmaxf(sqrtf(ss), 1e-12f);
    float4 g4 = ((const float4*)gamma)[lane];
    float4* ap = (float4*)(A + (size_t)t * 256) + lane;
    float4 a = *ap;
    a.x += gelu_f(v.x * inv * g4.x); a.y += gelu_f(v.y * inv * g4.y);
    a.z += gelu_f(v.z * inv * g4.z); a.w += gelu_f(v.w * inv * g4.w);
    *ap = a;
}

// ---------------- wave-per-token: end-score attn + head dot -> contribution ----------------
__global__ void endhead_kernel(const float* __restrict__ A, const float* __restrict__ w1,
                               const float* __restrict__ b1, const float* __restrict__ w2,
                               const float* __restrict__ b2, const float* __restrict__ hw,
                               const float* __restrict__ hb, float* __restrict__ contrib,
                               int T) {
    int wid = threadIdx.x >> 6, lane = threadIdx.x & 63;
    int t = blockIdx.x * 4 + wid;
    if (t >= T) return;
    float4 v = ((const float4*)(A + (size_t)t * 256))[lane];
    float p[8];
#pragma unroll
    for (int j = 0; j < 8; j++) p[j] = 0.0f;
    const float xv[4] = {v.x, v.y, v.z, v.w};
#pragma unroll
    for (int c = 0; c < 4; c++) {
        const float4* wr = (const float4*)(w1 + (4 * lane + c) * 8);
        float4 wa = wr[0], wb = wr[1];
        float xx = xv[c];
        p[0] += xx * wa.x; p[1] += xx * wa.y; p[2] += xx * wa.z; p[3] += xx * wa.w;
        p[4] += xx * wb.x; p[5] += xx * wb.y; p[6] += xx * wb.z; p[7] += xx * wb.w;
    }
    float4 h4 = ((const float4*)hw)[lane];
    float hp = gelu_f(v.x) * h4.x + gelu_f(v.y) * h4.y + gelu_f(v.z) * h4.z + gelu_f(v.w) * h4.w;
#pragma unroll
    for (int j = 0; j < 8; j++) p[j] = wave_reduce(p[j]);
    hp = wave_reduce(hp);
    if (lane == 0) {
        float z = b2[0];
#pragma unroll
        for (int j = 0; j < 8; j++) z += tanhf(p[j] + b1[j]) * w2[j];
        float sc = 1.0f / (1.0f + expf(-z));
        contrib[t] = (hp + hb[0]) * sc * (1.0f / (float)N1);
    }
}

// ---------------- per-batch sum of contributions + (block 0) load-balance loss --------
__global__ void finalsum_kernel(const float* __restrict__ contrib,
                                const float* __restrict__ imp, float* __restrict__ out) {
    int b = blockIdx.x, tid = threadIdx.x;
    __shared__ float red[4];
    const float* cb = contrib + (size_t)b * N1;
    float v = cb[tid] + cb[256 + tid];
    if (tid == 0) v += cb[512];
    float s = wave_reduce(v);
    int wid = tid >> 6, lane = tid & 63;
    if (lane == 0) red[wid] = s;
    __syncthreads();
    if (tid == 0) {
        out[b] = red[0] + red[1] + red[2] + red[3];
        if (b == 0) {
            float i0 = imp[0], i1 = imp[1], i2 = imp[2], i3 = imp[3];
            float mean = (i0 + i1 + i2 + i3) * 0.25f;
            float var = ((i0 - mean) * (i0 - mean) + (i1 - mean) * (i1 - mean) +
                         (i2 - mean) * (i2 - mean) + (i3 - mean) * (i3 - mean)) / 3.0f;
            out[64] = var / (mean * mean + 1e-10f);
        }
    }
}

extern "C" void kernel_launch(void* const* d_in, const int* in_sizes, int n_in,
                              void* d_out, int out_size, void* d_ws, size_t ws_size,
                              hipStream_t stream) {
    const float* x    = (const float*)d_in[0];
    const float* embw = (const float*)d_in[3];
    const float* embb = (const float*)d_in[4];
    const float* pos  = (const float*)d_in[5];
    const float* aw1  = (const float*)d_in[6];
    const float* ab1  = (const float*)d_in[7];
    const float* aw2  = (const float*)d_in[8];
    const float* ab2  = (const float*)d_in[9];
    const float* gw   = (const float*)d_in[10];
    const float* gb   = (const float*)d_in[11];
    const float* ew1  = (const float*)d_in[12];
    const float* eb1  = (const float*)d_in[13];
    const float* ew2  = (const float*)d_in[14];
    const float* eb2  = (const float*)d_in[15];
    const float* mg   = (const float*)d_in[16];
    const float* n1g  = (const float*)d_in[17];
    const float* n2g  = (const float*)d_in[18];
    const float* bott = (const float*)d_in[19];
    const float* cw39 = (const float*)d_in[20];
    const float* cw19 = (const float*)d_in[21];
    const float* cw9  = (const float*)d_in[22];
    const float* mpw  = (const float*)d_in[23];
    const float* bng  = (const float*)d_in[24];
    const float* bnb  = (const float*)d_in[25];
    const float* pjw  = (const float*)d_in[26];
    const float* pjb  = (const float*)d_in[27];
    const float* hw   = (const float*)d_in[28];
    const float* hb   = (const float*)d_in[29];
    float* out = (float*)d_out;

    float* W = (float*)d_ws;
    size_t off = 0;
    auto alloc = [&](size_t n) { float* p = W + off; off += n; return p; };
    float* A    = alloc((size_t)NTOK0 * 256);
    float* Bb   = alloc((size_t)NTOK0 * 256);
    float* CD   = alloc((size_t)NTOK1 * 256);
    float* XB   = alloc((size_t)NTOK0 * 32);
    float* sS   = alloc(NTOK0);
    float* ctb  = alloc(NTOK1);
    float* tval = alloc(NTOK1);
    float* imp  = alloc(4);
    float* part = alloc((size_t)BB * GCH * 4 * 256);
    off = (off + 3) & ~(size_t)3;  // 16B-align for short8 loads
    unsigned short* w1t  = (unsigned short*)(W + off); off += 262144 / 2;
    unsigned short* w2t  = (unsigned short*)(W + off); off += 262144 / 2;
    unsigned short* pjwb = (unsigned short*)(W + off); off += 65536 / 2;
    unsigned short* cwh  = (unsigned short*)(W + off); off += 137216 / 2;
    unsigned short* cwl  = (unsigned short*)(W + off); off += 137216 / 2;
    unsigned short* ewh  = (unsigned short*)(W + off); off += 32768 / 2;
    unsigned short* ewl  = (unsigned short*)(W + off); off += 32768 / 2;
    unsigned short* bth  = (unsigned short*)(W + off); off += 16384 / 2;
    unsigned short* btl  = (unsigned short*)(W + off); off += 16384 / 2;
    unsigned short* mph  = (unsigned short*)(W + off); off += 16384 / 2;
    unsigned short* mpl  = (unsigned short*)(W + off); off += 16384 / 2;
    int* selpos  = (int*)(W + off); off += (size_t)BB * 1024;
    int* buckets = (int*)(W + off); off += (size_t)4 * NTOK1;
    int* counts  = (int*)(W + off); off += 4;

    convert_bf16<<<3096, 256, 0, stream>>>(ew1, ew2, pjw, cw39, cw19, cw9, embw, bott, mpw,
                                           w1t, w2t, pjwb, cwh, cwl, ewh, ewl,
                                           bth, btl, mph, mpl, imp, counts);

    // ===== layer 0 (N=1023) =====
    embed_mfma<<<dim3(16, BB), 256, 0, stream>>>(x, ewh, ewl, embb, pos, A);
    norm_attn_kernel<<<NTOK0 / 4, 256, 0, stream>>>(A, A, nullptr, n1g, aw1, ab1, aw2, ab2,
                                                    1, 0, Bb, n2g, NTOK0);
    pw_mfma<<<dim3(32, BB), 256, 0, stream>>>(Bb, bth, btl, mph, mpl, bng, bnb, XB, CD, N0);
    conv_mfma<<<dim3(8, BB), 256, 0, stream>>>(XB, cwh, cwl, bng, bnb, CD, N0);
    proj_mfma<<<NTOK0 / 64, 256, 0, stream>>>(CD, pjwb, pjb, A, NTOK0);

    // ===== layer 1 (prune to 513 tokens); gelu fused into load =====
    norm_attn_kernel<<<NTOK0 / 4, 256, 0, stream>>>(A, Bb, sS, n1g + 256, aw1, ab1, aw2, ab2,
                                                    0, 1, nullptr, nullptr, NTOK0);
    topk_kernel<<<BB, 1024, 0, stream>>>(sS, selpos);
    scatter_kernel<<<dim3(GCH, BB), 256, 0, stream>>>(Bb, sS, selpos, A, part);
    extra_kernel<<<BB, 256, 0, stream>>>(part, A);
    rmsnorm_kernel<<<NTOK1 / 4, 256, 0, stream>>>(A, Bb, n2g + 256, NTOK1);
    gate_kernel<<<(NTOK1 + 255) / 256, 256, 0, stream>>>(Bb, gw, gb, tval, buckets, counts, imp,
                                                         NTOK1);
    ffn_kernel<<<dim3((NTOK1 + 63) / 64, 4), 256, 0, stream>>>(Bb, w1t, eb1, w2t, eb2, tval,
                                                               buckets, counts, CD, NTOK1);
    moe_add_kernel<<<NTOK1 / 4, 256, 0, stream>>>(CD, A, mg, NTOK1);
    pw_mfma<<<dim3((N1 + 31) / 32, BB), 256, 0, stream>>>(Bb, bth + 8192, btl + 8192,
                                                          mph + 8192, mpl + 8192,
                                                          bng + 128, bnb + 128, XB, CD, N1);
    conv_mfma<<<dim3((N1 + 127) / 128, BB), 256, 0, stream>>>(XB, cwh + 68608, cwl + 68608,
                                                              bng + 128, bnb + 128, CD, N1);
    proj_mfma<<<NTOK1 / 64, 256, 0, stream>>>(CD, pjwb + 32768, pjb + 256, A, NTOK1);
    endhead_kernel<<<NTOK1 / 4, 256, 0, stream>>>(A, aw1, ab1, aw2, ab2, hw, hb, ctb, NTOK1);
    finalsum_kernel<<<BB, 256, 0, stream>>>(ctb, imp, out);
}

// Round 8
// 733.586 us; speedup vs baseline: 1.2130x; 1.2130x over previous
//
#include <hip/hip_runtime.h>
#include <math.h>

#define BB 64
#define EMB 256
#define N0 1023
#define N1 513
#define NTOK0 (BB * N0)   // 65472
#define NTOK1 (BB * N1)   // 32832
#define GCH 16            // gather chunks per batch

typedef __attribute__((ext_vector_type(8))) short short8;
typedef __attribute__((ext_vector_type(4))) float f32x4;

__device__ __forceinline__ float gelu_f(float x) {
    return 0.5f * x * (1.0f + erff(x * 0.7071067811865476f));
}

__device__ __forceinline__ float4 gelu4(float4 v) {
    return make_float4(gelu_f(v.x), gelu_f(v.y), gelu_f(v.z), gelu_f(v.w));
}

__device__ __forceinline__ float wave_reduce(float v) {
#pragma unroll
    for (int o = 32; o > 0; o >>= 1) v += __shfl_down(v, o, 64);
    return v;
}

// bf16 helpers: pack with round-to-nearest-even; unpack = shift
__device__ __forceinline__ unsigned short f2bf(float f) {
    unsigned int u = __float_as_uint(f);
    u = (u + 0x7FFFu + ((u >> 16) & 1u)) >> 16;
    return (unsigned short)u;
}
__device__ __forceinline__ float bf2f(unsigned short h) {
    return __uint_as_float(((unsigned int)h) << 16);
}

// ---------------- convert weights to bf16 + init imp/counts ----------------
// conv layout per depth d: [branch][fo][k*32+fi]; b39 at 0, b19 at 39936, b9 at 59392.
// bott/mpw: already [d][f][dd] == desired [n][k] B-layout -> direct hi/lo split.
// proj: src [d][k=128][n=256] -> transposed [d][n][k] single bf16.
__global__ void convert_bf16(const float* __restrict__ ew1, const float* __restrict__ ew2,
                             const float* __restrict__ pjw,
                             const float* __restrict__ cw39, const float* __restrict__ cw19,
                             const float* __restrict__ cw9, const float* __restrict__ embw,
                             const float* __restrict__ bott, const float* __restrict__ mpw,
                             unsigned short* __restrict__ w1t, unsigned short* __restrict__ w2t,
                             unsigned short* __restrict__ pjwb,
                             unsigned short* __restrict__ cwh, unsigned short* __restrict__ cwl,
                             unsigned short* __restrict__ ewh, unsigned short* __restrict__ ewl,
                             unsigned short* __restrict__ bth, unsigned short* __restrict__ btl,
                             unsigned short* __restrict__ mph, unsigned short* __restrict__ mpl,
                             float* __restrict__ imp, int* __restrict__ counts) {
    int idx = blockIdx.x * 256 + threadIdx.x;
    if (blockIdx.x == 0 && threadIdx.x >= 252) {
        int i = threadIdx.x - 252;
        imp[i] = 0.0f; counts[i] = 0;
    }
    if (idx < 262144) {
        // out layout [e][n][k]; src [e][k][n]
        int e = idx >> 16, r = idx & 65535, n = r >> 8, k = r & 255;
        w1t[idx] = f2bf(ew1[(e << 16) + (k << 8) + n]);
    } else if (idx < 524288) {
        int j = idx - 262144;
        int e = j >> 16, r = j & 65535, n = r >> 8, k = r & 255;
        w2t[j] = f2bf(ew2[(e << 16) + (k << 8) + n]);
    } else if (idx < 589824) {
        // proj transposed: [d][n][k], src [d][k][n]
        int j = idx - 524288;
        int d = j >> 15, r = j & 32767, n = r >> 7, k = r & 127;
        pjwb[j] = f2bf(pjw[(d << 15) + (k << 8) + n]);
    } else if (idx < 727040) {
        int j = idx - 589824;
        int d = j / 68608, r = j % 68608;
        const float* src; int KT, rr;
        if (r < 39936)      { src = cw39; KT = 39; rr = r; }
        else if (r < 59392) { src = cw19; KT = 19; rr = r - 39936; }
        else                { src = cw9;  KT = 9;  rr = r - 59392; }
        int KK = KT * 32;
        int fo = rr / KK, jj = rr % KK, k = jj >> 5, fi = jj & 31;
        float w = src[(((d * 32 + fo) * 32) + fi) * KT + k];
        unsigned short h = f2bf(w);
        cwh[j] = h;
        cwl[j] = f2bf(w - bf2f(h));
    } else if (idx < 759808) {
        // embw is already [e][k] (k = c*8+s), 256*128
        int j = idx - 727040;
        float w = embw[j];
        unsigned short h = f2bf(w);
        ewh[j] = h;
        ewl[j] = f2bf(w - bf2f(h));
    } else if (idx < 776192) {
        int j = idx - 759808;
        float w = bott[j];
        unsigned short h = f2bf(w);
        bth[j] = h;
        btl[j] = f2bf(w - bf2f(h));
    } else if (idx < 792576) {
        int j = idx - 776192;
        float w = mpw[j];
        unsigned short h = f2bf(w);
        mph[j] = h;
        mpl[j] = f2bf(w - bf2f(h));
    }
}

// ---------------- embedding conv via MFMA: im2col in LDS, hi/lo bf16 ----------------
__global__ __launch_bounds__(256, 2)
void embed_mfma(const float* __restrict__ x, const unsigned short* __restrict__ ewh,
                const unsigned short* __restrict__ ewl, const float* __restrict__ emb_b,
                const float* __restrict__ pos, float* __restrict__ A) {
    int b = blockIdx.y;
    int n0 = blockIdx.x * 64;
    __shared__ __align__(16) unsigned short tokh[64 * 128];  // 16 KB
    __shared__ __align__(16) unsigned short tokl[64 * 128];  // 16 KB
    int tid = threadIdx.x;
#pragma unroll
    for (int it = 0; it < 4; it++) {
        int idx = tid + it * 256;
        int m = idx & 63, c = idx >> 6;
        int tok = n0 + m;
        float v[8] = {0.f, 0.f, 0.f, 0.f, 0.f, 0.f, 0.f, 0.f};
        if (tok < N0) {
            const float* p = x + ((size_t)b * 16 + c) * 4096 + 4 * tok;
            float4 a = *(const float4*)p;
            float4 bq = *(const float4*)(p + 4);
            v[0] = a.x; v[1] = a.y; v[2] = a.z; v[3] = a.w;
            v[4] = bq.x; v[5] = bq.y; v[6] = bq.z; v[7] = bq.w;
        }
        short8 hv, lv;
#pragma unroll
        for (int j = 0; j < 8; j++) {
            unsigned short hh = f2bf(v[j]);
            hv[j] = (short)hh;
            lv[j] = (short)f2bf(v[j] - bf2f(hh));
        }
        int si = (m << 7) + ((c << 3) ^ ((m & 7) << 3));
        *(short8*)(&tokh[si]) = hv;
        *(short8*)(&tokl[si]) = lv;
    }
    __syncthreads();

    int lane = tid & 63, wid = tid >> 6;
    int nb = wid << 6;                 // wave's 64-col emb slice
    int arow = lane & 15;
    int kgrp = (lane >> 4) << 3;
    int rb = (lane >> 4) << 2;

    f32x4 acc[4][4];
#pragma unroll
    for (int mt = 0; mt < 4; mt++)
#pragma unroll
        for (int nt = 0; nt < 4; nt++) acc[mt][nt] = f32x4{0.f, 0.f, 0.f, 0.f};

    for (int ks = 0; ks < 4; ks++) {
        int kk = (ks << 5) + kgrp;
        short8 ah[4], al[4], bh[4], bl[4];
#pragma unroll
        for (int mt = 0; mt < 4; mt++) {
            int m = (mt << 4) + arow;
            int si = (m << 7) + (kk ^ ((m & 7) << 3));
            ah[mt] = *(const short8*)(&tokh[si]);
            al[mt] = *(const short8*)(&tokl[si]);
        }
#pragma unroll
        for (int nt = 0; nt < 4; nt++) {
            int n = nb + (nt << 4) + arow;
            bh[nt] = *(const short8*)(&ewh[(n << 7) + kk]);
            bl[nt] = *(const short8*)(&ewl[(n << 7) + kk]);
        }
#pragma unroll
        for (int mt = 0; mt < 4; mt++) {
#pragma unroll
            for (int nt = 0; nt < 4; nt++) {
                acc[mt][nt] = __builtin_amdgcn_mfma_f32_16x16x32_bf16(ah[mt], bh[nt], acc[mt][nt], 0, 0, 0);
                acc[mt][nt] = __builtin_amdgcn_mfma_f32_16x16x32_bf16(al[mt], bh[nt], acc[mt][nt], 0, 0, 0);
                acc[mt][nt] = __builtin_amdgcn_mfma_f32_16x16x32_bf16(ah[mt], bl[nt], acc[mt][nt], 0, 0, 0);
            }
        }
    }

    float eb[4];
#pragma unroll
    for (int nt = 0; nt < 4; nt++) eb[nt] = emb_b[nb + (nt << 4) + arow];
#pragma unroll
    for (int mt = 0; mt < 4; mt++) {
#pragma unroll
        for (int nt = 0; nt < 4; nt++) {
            int n = nb + (nt << 4) + arow;
#pragma unroll
            for (int r = 0; r < 4; r++) {
                int m = (mt << 4) + rb + r;
                int tok = n0 + m;
                if (tok < N0)
                    A[((size_t)b * N0 + tok) * 256 + n] =
                        acc[mt][nt][r] + eb[nt] + pos[(size_t)tok * 256 + n];
            }
        }
    }
}

// ---------------- wave-per-token: rmsnorm + attn score (+pregelu, +second norm) ------
__global__ void norm_attn_kernel(const float* __restrict__ in, float* __restrict__ outv,
                                 float* __restrict__ score_out, const float* __restrict__ g,
                                 const float* __restrict__ w1, const float* __restrict__ b1,
                                 const float* __restrict__ w2, const float* __restrict__ b2,
                                 int scale_out, int pregelu,
                                 float* __restrict__ outv2, const float* __restrict__ g2,
                                 int T) {
    int wid = threadIdx.x >> 6, lane = threadIdx.x & 63;
    int t = blockIdx.x * 4 + wid;
    if (t >= T) return;
    float4 v = ((const float4*)(in + (size_t)t * 256))[lane];
    if (pregelu) v = gelu4(v);
    float4 xn = v;
    if (g != nullptr) {
        float ss = v.x * v.x + v.y * v.y + v.z * v.z + v.w * v.w;
        ss = wave_reduce(ss);
        ss = __shfl(ss, 0, 64);
        float inv = 16.0f / fmaxf(sqrtf(ss), 1e-12f);
        float4 g4 = ((const float4*)g)[lane];
        xn.x = v.x * inv * g4.x; xn.y = v.y * inv * g4.y;
        xn.z = v.z * inv * g4.z; xn.w = v.w * inv * g4.w;
    }
    float p[8];
#pragma unroll
    for (int j = 0; j < 8; j++) p[j] = 0.0f;
    const float xv[4] = {xn.x, xn.y, xn.z, xn.w};
#pragma unroll
    for (int c = 0; c < 4; c++) {
        const float4* wr = (const float4*)(w1 + (4 * lane + c) * 8);
        float4 wa = wr[0], wb = wr[1];
        float xx = xv[c];
        p[0] += xx * wa.x; p[1] += xx * wa.y; p[2] += xx * wa.z; p[3] += xx * wa.w;
        p[4] += xx * wb.x; p[5] += xx * wb.y; p[6] += xx * wb.z; p[7] += xx * wb.w;
    }
#pragma unroll
    for (int j = 0; j < 8; j++) p[j] = wave_reduce(p[j]);
    float sc = 0.0f;
    if (lane == 0) {
        float z = b2[0];
#pragma unroll
        for (int j = 0; j < 8; j++) z += tanhf(p[j] + b1[j]) * w2[j];
        sc = 1.0f / (1.0f + expf(-z));
        if (score_out) score_out[t] = sc;
    }
    sc = __shfl(sc, 0, 64);
    if (outv) {
        float m = scale_out ? sc : 1.0f;
        float4 o = make_float4(xn.x * m, xn.y * m, xn.z * m, xn.w * m);
        ((float4*)(outv + (size_t)t * 256))[lane] = o;
    }
    if (outv2) {
        float ss2 = xn.x * xn.x + xn.y * xn.y + xn.z * xn.z + xn.w * xn.w;
        ss2 = wave_reduce(ss2);
        ss2 = __shfl(ss2, 0, 64);
        float inv2 = 16.0f / fmaxf(sqrtf(ss2), 1e-12f);
        float4 q4 = ((const float4*)g2)[lane];
        float4 o;
        o.x = xn.x * inv2 * q4.x; o.y = xn.y * inv2 * q4.y;
        o.z = xn.z * inv2 * q4.z; o.w = xn.w * inv2 * q4.w;
        ((float4*)(outv2 + (size_t)t * 256))[lane] = o;
    }
}

// ---------------- wave-per-token rmsnorm ----------------
__global__ void rmsnorm_kernel(const float* __restrict__ in, float* __restrict__ out,
                               const float* __restrict__ g, int T) {
    int wid = threadIdx.x >> 6, lane = threadIdx.x & 63;
    int t = blockIdx.x * 4 + wid;
    if (t >= T) return;
    float4 v = ((const float4*)(in + (size_t)t * 256))[lane];
    float ss = v.x * v.x + v.y * v.y + v.z * v.z + v.w * v.w;
    ss = wave_reduce(ss);
    ss = __shfl(ss, 0, 64);
    float inv = 16.0f / fmaxf(sqrtf(ss), 1e-12f);
    float4 g4 = ((const float4*)g)[lane];
    float4 o;
    o.x = v.x * inv * g4.x; o.y = v.y * inv * g4.y;
    o.z = v.z * inv * g4.z; o.w = v.w * inv * g4.w;
    ((float4*)(out + (size_t)t * 256))[lane] = o;
}

// ---------------- pointwise bottleneck + maxpool via MFMA, hi/lo bf16 ----------------
__global__ __launch_bounds__(256, 2)
void pw_mfma(const float* __restrict__ xn, const unsigned short* __restrict__ bwh,
             const unsigned short* __restrict__ bwl, const unsigned short* __restrict__ mwh,
             const unsigned short* __restrict__ mwl, const float* __restrict__ bng,
             const float* __restrict__ bnb, float* __restrict__ xb,
             float* __restrict__ cat, int N) {
    int b = blockIdx.y;
    int t0 = blockIdx.x * 32;
    __shared__ __align__(16) unsigned short xth[34 * 256];
    __shared__ __align__(16) unsigned short xtl[34 * 256];
    __shared__ __align__(16) unsigned short xmh[32 * 256];
    __shared__ __align__(16) unsigned short xml[32 * 256];
    const float* xbase = xn + (size_t)b * N * 256;
    int tid = threadIdx.x;
    // stage xt rows (tokens t0-1 .. t0+32), hi/lo, swizzled; OOB = -inf (hi), 0 (lo)
    for (int idx = tid; idx < 34 * 32; idx += 256) {
        int r = idx >> 5, p = (idx & 31) << 3;
        int t = t0 - 1 + r;
        short8 hv, lv;
        if (t >= 0 && t < N) {
            const float4* q = (const float4*)(xbase + (size_t)t * 256 + p);
            float4 a = q[0], c = q[1];
            float v[8] = {a.x, a.y, a.z, a.w, c.x, c.y, c.z, c.w};
#pragma unroll
            for (int j = 0; j < 8; j++) {
                unsigned short hh = f2bf(v[j]);
                hv[j] = (short)hh;
                lv[j] = (short)f2bf(v[j] - bf2f(hh));
            }
        } else {
#pragma unroll
            for (int j = 0; j < 8; j++) { hv[j] = (short)0xFF80; lv[j] = 0; }
        }
        int si = (r << 8) + (p ^ ((r & 7) << 3));
        *(short8*)(&xth[si]) = hv;
        *(short8*)(&xtl[si]) = lv;
    }
    __syncthreads();
    // xm[r] = rowwise max of xt rows r, r+1, r+2 (tokens t-1, t, t+1)
    for (int idx = tid; idx < 32 * 32; idx += 256) {
        int r = idx >> 5, p = (idx & 31) << 3;
        int s0 = ((r + 0) << 8) + (p ^ (((r + 0) & 7) << 3));
        int s1 = ((r + 1) << 8) + (p ^ (((r + 1) & 7) << 3));
        int s2 = ((r + 2) << 8) + (p ^ (((r + 2) & 7) << 3));
        short8 h0 = *(const short8*)(&xth[s0]), l0 = *(const short8*)(&xtl[s0]);
        short8 h1 = *(const short8*)(&xth[s1]), l1 = *(const short8*)(&xtl[s1]);
        short8 h2 = *(const short8*)(&xth[s2]), l2 = *(const short8*)(&xtl[s2]);
        short8 hv, lv;
#pragma unroll
        for (int j = 0; j < 8; j++) {
            float a = bf2f((unsigned short)h0[j]) + bf2f((unsigned short)l0[j]);
            float c = bf2f((unsigned short)h1[j]) + bf2f((unsigned short)l1[j]);
            float d = bf2f((unsigned short)h2[j]) + bf2f((unsigned short)l2[j]);
            float m = fmaxf(fmaxf(a, c), d);
            unsigned short hh = f2bf(m);
            hv[j] = (short)hh;
            lv[j] = (short)f2bf(m - bf2f(hh));
        }
        int si = (r << 8) + (p ^ ((r & 7) << 3));
        *(short8*)(&xmh[si]) = hv;
        *(short8*)(&xml[si]) = lv;
    }
    __syncthreads();

    int lane = tid & 63, wid = tid >> 6;
    int mt = wid & 1, path = wid >> 1;   // path 0 = bottleneck, 1 = maxpool
    int arow = lane & 15, kgrp = (lane >> 4) << 3, rb = (lane >> 4) << 2;
    const unsigned short* Wh = path ? mwh : bwh;
    const unsigned short* Wl = path ? mwl : bwl;
    f32x4 acc[2];
    acc[0] = f32x4{0.f, 0.f, 0.f, 0.f};
    acc[1] = f32x4{0.f, 0.f, 0.f, 0.f};

    int m = (mt << 4) + arow;
    int rowA = path ? m : (m + 1);   // bott reads xt row m+1 (token t0+m); mp reads xm row m
    const unsigned short* Ah = path ? xmh : xth;
    const unsigned short* Al = path ? xml : xtl;
    for (int ks = 0; ks < 8; ks++) {
        int kk = (ks << 5) + kgrp;
        int si = (rowA << 8) + (kk ^ ((rowA & 7) << 3));
        short8 ah = *(const short8*)(&Ah[si]);
        short8 al = *(const short8*)(&Al[si]);
#pragma unroll
        for (int nt = 0; nt < 2; nt++) {
            int n = (nt << 4) + arow;
            short8 bh = *(const short8*)(&Wh[n * 256 + kk]);
            short8 bl = *(const short8*)(&Wl[n * 256 + kk]);
            acc[nt] = __builtin_amdgcn_mfma_f32_16x16x32_bf16(ah, bh, acc[nt], 0, 0, 0);
            acc[nt] = __builtin_amdgcn_mfma_f32_16x16x32_bf16(al, bh, acc[nt], 0, 0, 0);
            acc[nt] = __builtin_amdgcn_mfma_f32_16x16x32_bf16(ah, bl, acc[nt], 0, 0, 0);
        }
    }

    const float BN_DIV = 1.0000050f;
    if (path == 0) {
#pragma unroll
        for (int nt = 0; nt < 2; nt++) {
            int n = (nt << 4) + arow;
#pragma unroll
            for (int r = 0; r < 4; r++) {
                int t = t0 + (mt << 4) + rb + r;
                if (t < N) xb[((size_t)b * N + t) * 32 + n] = acc[nt][r];
            }
        }
    } else {
#pragma unroll
        for (int nt = 0; nt < 2; nt++) {
            int n = (nt << 4) + arow;
            float scl = bng[96 + n] / BN_DIV;
            float sh = bnb[96 + n];
#pragma unroll
            for (int r = 0; r < 4; r++) {
                int t = t0 + (mt << 4) + rb + r;
                if (t < N)
                    cat[((size_t)b * N + t) * 128 + 96 + n] = gelu_f(acc[nt][r] * scl + sh);
            }
        }
    }
}

// ---------------- inception time-convs via MFMA, split hi/lo bf16 ----------------
// Block: 128 output tokens (4 waves x 2 m-tiles x 16), all 3 branches, 32 fo each.
__global__ __launch_bounds__(256, 2)
void conv_mfma(const float* __restrict__ xb, const unsigned short* __restrict__ wh,
               const unsigned short* __restrict__ wl, const float* __restrict__ bng,
               const float* __restrict__ bnb, float* __restrict__ cat, int N) {
    int b = blockIdx.y;
    int t0 = blockIdx.x * 128;
    __shared__ __align__(16) unsigned short tokh[167 * 32];
    __shared__ __align__(16) unsigned short tokl[167 * 32];
    const float* xbase = xb + (size_t)b * N * 32;
    int tid = threadIdx.x;
    for (int idx = tid; idx < 167 * 16; idx += 256) {
        int r = idx >> 4, c = (idx & 15) << 1;
        int t = t0 - 19 + r;
        float vx = 0.f, vy = 0.f;
        if (t >= 0 && t < N) {
            const float2 v = *(const float2*)(xbase + (size_t)t * 32 + c);
            vx = v.x; vy = v.y;
        }
        unsigned short h0 = f2bf(vx), h1 = f2bf(vy);
        unsigned short l0 = f2bf(vx - bf2f(h0)), l1 = f2bf(vy - bf2f(h1));
        int si = (r << 5) + ((((c >> 3) ^ ((r >> 1) & 3)) << 3) | (c & 7));
        *(unsigned int*)(&tokh[si]) = (unsigned)h0 | ((unsigned)h1 << 16);
        *(unsigned int*)(&tokl[si]) = (unsigned)l0 | ((unsigned)l1 << 16);
    }
    __syncthreads();
    int lane = tid & 63, wid = tid >> 6;
    int arow = lane & 15, g = lane >> 4, kgrp = g << 3;
    int rb = g << 2;
    f32x4 acc[3][2][2];
#pragma unroll
    for (int i = 0; i < 3; i++)
#pragma unroll
        for (int m = 0; m < 2; m++) {
            acc[i][m][0] = f32x4{0.f, 0.f, 0.f, 0.f};
            acc[i][m][1] = f32x4{0.f, 0.f, 0.f, 0.f};
        }

#define SIA(row) (((row) << 5) + ((g ^ (((row) >> 1) & 3)) << 3))
#define CONV_BR(KT, BOFF, WOFF, BR)                                                        \
    {                                                                                      \
        const int KK = (KT) * 32;                                                          \
        int r0 = (WOFF) + wid * 32 + arow;                                                 \
        const unsigned short* whp = wh + (BOFF) + arow * KK + kgrp;                        \
        const unsigned short* wlp = wl + (BOFF) + arow * KK + kgrp;                        \
        for (int k = 0; k < (KT); k++) {                                                   \
            int ra = r0 + k, rc = r0 + 16 + k;                                             \
            short8 ah0 = *(const short8*)(&tokh[SIA(ra)]);                                 \
            short8 al0 = *(const short8*)(&tokl[SIA(ra)]);                                 \
            short8 ah1 = *(const short8*)(&tokh[SIA(rc)]);                                 \
            short8 al1 = *(const short8*)(&tokl[SIA(rc)]);                                 \
            short8 bh0 = *(const short8*)(&whp[k * 32]);                                   \
            short8 bl0 = *(const short8*)(&wlp[k * 32]);                                   \
            short8 bh1 = *(const short8*)(&whp[16 * KK + k * 32]);                         \
            short8 bl1 = *(const short8*)(&wlp[16 * KK + k * 32]);                         \
            acc[BR][0][0] = __builtin_amdgcn_mfma_f32_16x16x32_bf16(ah0, bh0, acc[BR][0][0], 0, 0, 0); \
            acc[BR][0][1] = __builtin_amdgcn_mfma_f32_16x16x32_bf16(ah0, bh1, acc[BR][0][1], 0, 0, 0); \
            acc[BR][0][0] = __builtin_amdgcn_mfma_f32_16x16x32_bf16(al0, bh0, acc[BR][0][0], 0, 0, 0); \
            acc[BR][0][1] = __builtin_amdgcn_mfma_f32_16x16x32_bf16(al0, bh1, acc[BR][0][1], 0, 0, 0); \
            acc[BR][0][0] = __builtin_amdgcn_mfma_f32_16x16x32_bf16(ah0, bl0, acc[BR][0][0], 0, 0, 0); \
            acc[BR][0][1] = __builtin_amdgcn_mfma_f32_16x16x32_bf16(ah0, bl1, acc[BR][0][1], 0, 0, 0); \
            acc[BR][1][0] = __builtin_amdgcn_mfma_f32_16x16x32_bf16(ah1, bh0, acc[BR][1][0], 0, 0, 0); \
            acc[BR][1][1] = __builtin_amdgcn_mfma_f32_16x16x32_bf16(ah1, bh1, acc[BR][1][1], 0, 0, 0); \
            acc[BR][1][0] = __builtin_amdgcn_mfma_f32_16x16x32_bf16(al1, bh0, acc[BR][1][0], 0, 0, 0); \
            acc[BR][1][1] = __builtin_amdgcn_mfma_f32_16x16x32_bf16(al1, bh1, acc[BR][1][1], 0, 0, 0); \
            acc[BR][1][0] = __builtin_amdgcn_mfma_f32_16x16x32_bf16(ah1, bl0, acc[BR][1][0], 0, 0, 0); \
            acc[BR][1][1] = __builtin_amdgcn_mfma_f32_16x16x32_bf16(ah1, bl1, acc[BR][1][1], 0, 0, 0); \
        }                                                                                  \
    }

    CONV_BR(39, 0, 0, 0)
    CONV_BR(19, 39936, 10, 1)
    CONV_BR(9, 59392, 15, 2)
#undef CONV_BR
#undef SIA

    const float BN_DIV = 1.0000050f;
    const int COFFS[3] = {0, 32, 64};
#pragma unroll
    for (int br = 0; br < 3; br++) {
#pragma unroll
        for (int mt = 0; mt < 2; mt++) {
#pragma unroll
            for (int nt = 0; nt < 2; nt++) {
                int fo = COFFS[br] + nt * 16 + arow;
                float scl = bng[fo] / BN_DIV;
                float sh = bnb[fo];
#pragma unroll
                for (int r = 0; r < 4; r++) {
                    int t = t0 + wid * 32 + mt * 16 + rb + r;
                    if (t < N)
                        cat[((size_t)b * N + t) * 128 + fo] =
                            gelu_f(acc[br][mt][nt][r] * scl + sh);
                }
            }
        }
    }
}

// ---------------- proj via MFMA: K=128, hi/lo bf16 activations, bf16 weights ----------
__global__ __launch_bounds__(256, 2)
void proj_mfma(const float* __restrict__ cat, const unsigned short* __restrict__ pjt,
               const float* __restrict__ pb, float* __restrict__ A, int TN) {
    int t0 = blockIdx.x * 64;
    __shared__ __align__(16) unsigned short tokh[64 * 128];  // 16 KB
    __shared__ __align__(16) unsigned short tokl[64 * 128];  // 16 KB
    int tid = threadIdx.x;
#pragma unroll
    for (int it = 0; it < 4; it++) {
        int idx = tid + it * 256;
        int m = idx >> 4, c = idx & 15;
        int t = t0 + m;
        float v[8] = {0.f, 0.f, 0.f, 0.f, 0.f, 0.f, 0.f, 0.f};
        if (t < TN) {
            const float4* q = (const float4*)(cat + (size_t)t * 128 + (c << 3));
            float4 a = q[0], bq = q[1];
            v[0] = a.x; v[1] = a.y; v[2] = a.z; v[3] = a.w;
            v[4] = bq.x; v[5] = bq.y; v[6] = bq.z; v[7] = bq.w;
        }
        short8 hv, lv;
#pragma unroll
        for (int j = 0; j < 8; j++) {
            unsigned short hh = f2bf(v[j]);
            hv[j] = (short)hh;
            lv[j] = (short)f2bf(v[j] - bf2f(hh));
        }
        int si = (m << 7) + ((c << 3) ^ ((m & 7) << 3));
        *(short8*)(&tokh[si]) = hv;
        *(short8*)(&tokl[si]) = lv;
    }
    __syncthreads();

    int lane = tid & 63, wid = tid >> 6;
    int nb = wid << 6;
    int arow = lane & 15;
    int kgrp = (lane >> 4) << 3;
    int rb = (lane >> 4) << 2;

    f32x4 acc[4][4];
#pragma unroll
    for (int mt = 0; mt < 4; mt++)
#pragma unroll
        for (int nt = 0; nt < 4; nt++) acc[mt][nt] = f32x4{0.f, 0.f, 0.f, 0.f};

    for (int ks = 0; ks < 4; ks++) {
        int kk = (ks << 5) + kgrp;
        short8 ah[4], al[4], bw[4];
#pragma unroll
        for (int mt = 0; mt < 4; mt++) {
            int m = (mt << 4) + arow;
            int si = (m << 7) + (kk ^ ((m & 7) << 3));
            ah[mt] = *(const short8*)(&tokh[si]);
            al[mt] = *(const short8*)(&tokl[si]);
        }
#pragma unroll
        for (int nt = 0; nt < 4; nt++) {
            int n = nb + (nt << 4) + arow;
            bw[nt] = *(const short8*)(&pjt[(n << 7) + kk]);
        }
#pragma unroll
        for (int mt = 0; mt < 4; mt++) {
#pragma unroll
            for (int nt = 0; nt < 4; nt++) {
                acc[mt][nt] = __builtin_amdgcn_mfma_f32_16x16x32_bf16(ah[mt], bw[nt], acc[mt][nt], 0, 0, 0);
                acc[mt][nt] = __builtin_amdgcn_mfma_f32_16x16x32_bf16(al[mt], bw[nt], acc[mt][nt], 0, 0, 0);
            }
        }
    }

    float bias[4];
#pragma unroll
    for (int nt = 0; nt < 4; nt++) bias[nt] = pb[nb + (nt << 4) + arow];
#pragma unroll
    for (int mt = 0; mt < 4; mt++) {
#pragma unroll
        for (int nt = 0; nt < 4; nt++) {
            int n = nb + (nt << 4) + arow;
#pragma unroll
            for (int r = 0; r < 4; r++) {
                int t = t0 + (mt << 4) + rb + r;
                if (t < TN) {
                    float* ap = A + (size_t)t * 256 + n;
                    *ap += acc[mt][nt][r] + bias[nt];
                }
            }
        }
    }
}

// ---------------- top-512-of-1023 per batch ----------------
__global__ __launch_bounds__(1024) void topk_kernel(const float* __restrict__ s,
                                                    int* __restrict__ selpos) {
    int b = blockIdx.x;
    int tid = threadIdx.x;
    __shared__ float srt[1024];
    __shared__ int buf[1024];
    __shared__ int Gtot_s;
    float val = (tid < N0) ? s[(size_t)b * N0 + tid] : -INFINITY;
    srt[tid] = val;
    __syncthreads();
    for (int ksz = 2; ksz <= 1024; ksz <<= 1) {
        for (int j = ksz >> 1; j > 0; j >>= 1) {
            int ixj = tid ^ j;
            if (ixj > tid) {
                float a = srt[tid], c = srt[ixj];
                bool up = ((tid & ksz) == 0);
                if ((a > c) == up) { srt[tid] = c; srt[ixj] = a; }
            }
            __syncthreads();
        }
    }
    float thr = srt[512];
    __syncthreads();
    int isG = (val > thr) ? 1 : 0;
    int isE = (val == thr) ? 1 : 0;
    buf[tid] = isG;
    __syncthreads();
    for (int off = 1; off < 1024; off <<= 1) {
        int cur = buf[tid];
        int add = (tid >= off) ? buf[tid - off] : 0;
        __syncthreads();
        buf[tid] = cur + add;
        __syncthreads();
    }
    if (tid == 0) Gtot_s = buf[1023];
    __syncthreads();
    int Gtot = Gtot_s;
    int Eneed = 512 - Gtot;
    buf[tid] = isE;
    __syncthreads();
    for (int off = 1; off < 1024; off <<= 1) {
        int cur = buf[tid];
        int add = (tid >= off) ? buf[tid - off] : 0;
        __syncthreads();
        buf[tid] = cur + add;
        __syncthreads();
    }
    int eqExcl = buf[tid] - isE;
    int sel = (isG || (isE && eqExcl < Eneed)) ? 1 : 0;
    __syncthreads();
    buf[tid] = sel;
    __syncthreads();
    for (int off = 1; off < 1024; off <<= 1) {
        int cur = buf[tid];
        int add = (tid >= off) ? buf[tid - off] : 0;
        __syncthreads();
        buf[tid] = cur + add;
        __syncthreads();
    }
    int pos = buf[tid] - sel;
    selpos[b * 1024 + tid] = sel ? pos : -1;
}

// ---------------- scatter: 4 token-groups x float4; 4 partials per chunk ----------------
__global__ void scatter_kernel(const float* __restrict__ xn, const float* __restrict__ s,
                               const int* __restrict__ selpos, float* __restrict__ A,
                               float* __restrict__ part) {
    int b = blockIdx.y;
    int chunk = blockIdx.x;
    int wid = threadIdx.x >> 6, lane = threadIdx.x & 63;
    int t0 = chunk * 64;
    __shared__ float sl[64];
    __shared__ int pl[64];
    if (threadIdx.x < 64) {
        int t = t0 + threadIdx.x;
        sl[threadIdx.x] = (t < N0) ? s[(size_t)b * N0 + t] : 0.0f;
        pl[threadIdx.x] = (t < N0) ? selpos[b * 1024 + t] : -1;
    }
    __syncthreads();
    const float* xbase = xn + ((size_t)b * N0 + t0) * 256;
    float* obase = A + (size_t)b * N1 * 256;
    float4 nonsel = make_float4(0.f, 0.f, 0.f, 0.f);
    int tmax = (t0 + 64 <= N0) ? 64 : (N0 - t0);
    for (int i = wid; i < tmax; i += 4) {
        float sc = sl[i];
        float4 v = ((const float4*)(xbase + (size_t)i * 256))[lane];
        v.x *= sc; v.y *= sc; v.z *= sc; v.w *= sc;
        int p = pl[i];
        if (p >= 0) ((float4*)(obase + (size_t)p * 256))[lane] = v;
        else { nonsel.x += v.x; nonsel.y += v.y; nonsel.z += v.z; nonsel.w += v.w; }
    }
    ((float4*)(part + ((size_t)(b * GCH + chunk) * 4 + wid) * 256))[lane] = nonsel;
}

// ---------------- reduce chunk partials (64 per batch) -> extra row ----------------
__global__ void extra_kernel(const float* __restrict__ part, float* __restrict__ A) {
    int b = blockIdx.x, d = threadIdx.x;
    float acc = 0.0f;
    for (int c = 0; c < GCH * 4; c++) acc += part[((size_t)b * GCH * 4 + c) * 256 + d];
    A[((size_t)b * N1 + 512) * 256 + d] = acc;
}

// ---------------- gate: one token per thread, block-aggregated routing ----------------
__global__ void gate_kernel(const float* __restrict__ xn2, const float* __restrict__ gw,
                            const float* __restrict__ gb, float* __restrict__ topval,
                            int* __restrict__ buckets, int* __restrict__ counts,
                            float* __restrict__ imp, int T) {
    int tid = threadIdx.x;
    int t = blockIdx.x * 256 + tid;
    __shared__ float4 gws[256];
    __shared__ int lcount[4];
    __shared__ int lbase[4];
    __shared__ float limp[4];
    gws[tid] = ((const float4*)gw)[tid];
    if (tid < 4) { lcount[tid] = 0; limp[tid] = 0.0f; }
    __syncthreads();
    bool valid = (t < T);
    float a0 = 0, a1 = 0, a2 = 0, a3 = 0;
    if (valid) {
        const float4* xb4 = (const float4*)(xn2 + (size_t)t * 256);
#pragma unroll 8
        for (int d4 = 0; d4 < 64; d4++) {
            float4 xv = xb4[d4];
            float4 w0 = gws[4 * d4], w1 = gws[4 * d4 + 1];
            float4 w2 = gws[4 * d4 + 2], w3 = gws[4 * d4 + 3];
            a0 += xv.x * w0.x + xv.y * w1.x + xv.z * w2.x + xv.w * w3.x;
            a1 += xv.x * w0.y + xv.y * w1.y + xv.z * w2.y + xv.w * w3.y;
            a2 += xv.x * w0.z + xv.y * w1.z + xv.z * w2.z + xv.w * w3.z;
            a3 += xv.x * w0.w + xv.y * w1.w + xv.z * w2.w + xv.w * w3.w;
        }
    }
    float q0 = 0, q1 = 0, q2 = 0, q3 = 0;
    int eid = 0;
    int lrank = 0;
    if (valid) {
        float l0 = a0 + gb[0], l1 = a1 + gb[1], l2 = a2 + gb[2], l3 = a3 + gb[3];
        float m = fmaxf(fmaxf(l0, l1), fmaxf(l2, l3));
        float e0 = expf(l0 - m), e1 = expf(l1 - m), e2 = expf(l2 - m), e3 = expf(l3 - m);
        float ssum = e0 + e1 + e2 + e3;
        q0 = e0 / ssum; q1 = e1 / ssum; q2 = e2 / ssum; q3 = e3 / ssum;
        float bv = q0;
        if (q1 > bv) { bv = q1; eid = 1; }
        if (q2 > bv) { bv = q2; eid = 2; }
        if (q3 > bv) { bv = q3; eid = 3; }
        topval[t] = bv;
        lrank = atomicAdd(&lcount[eid], 1);
    }
    float r0 = wave_reduce(q0), r1 = wave_reduce(q1);
    float r2 = wave_reduce(q2), r3 = wave_reduce(q3);
    if ((tid & 63) == 0) {
        atomicAdd(&limp[0], r0); atomicAdd(&limp[1], r1);
        atomicAdd(&limp[2], r2); atomicAdd(&limp[3], r3);
    }
    __syncthreads();
    if (tid < 4) {
        lbase[tid] = atomicAdd(&counts[tid], lcount[tid]);
        atomicAdd(&imp[tid], limp[tid]);
    }
    __syncthreads();
    if (valid) buckets[eid * T + lbase[eid] + lrank] = t;
}

// ---------------- expert FFN: MFMA bf16, split hi/lo activations ----------------
// 32-token tile, 8 waves (512 thr), 32.3 KB LDS -> 4 blocks/CU = 32 waves/CU (100% cap).
// Wave owns a 32-col N-slice (8 x 32 = 256). Same swizzle + accumulation order as the
// proven 64-token version -> bit-identical results.
__global__ __launch_bounds__(512, 1)
void ffn_kernel(const float* __restrict__ xn2, const unsigned short* __restrict__ w1t,
                const float* __restrict__ b1, const unsigned short* __restrict__ w2t,
                const float* __restrict__ b2, const float* __restrict__ topval,
                const int* __restrict__ buckets, const int* __restrict__ counts,
                float* __restrict__ C, int T) {
    int e = blockIdx.y;
    int cnt = counts[e];
    int base = blockIdx.x * 32;
    if (base >= cnt) return;
    __shared__ __align__(16) unsigned short tokh[32 * 256];  // 16 KB
    __shared__ __align__(16) unsigned short tokl[32 * 256];  // 16 KB
    __shared__ int tids[32];
    __shared__ float tv[32];
    int tid = threadIdx.x;
    if (tid < 32) {
        int idx = base + tid;
        int t = (idx < cnt) ? buckets[e * T + idx] : -1;
        tids[tid] = t;
        tv[tid] = (t >= 0) ? topval[t] : 0.0f;
    }
    __syncthreads();
#pragma unroll
    for (int it = 0; it < 2; it++) {
        int cc = tid + it * 512;
        int m = cc >> 5, d0 = (cc & 31) << 3;
        int t = tids[m];
        float4 a = make_float4(0.f, 0.f, 0.f, 0.f), b = a;
        if (t >= 0) {
            const float4* p = (const float4*)(xn2 + (size_t)t * 256 + d0);
            a = p[0]; b = p[1];
        }
        float v[8] = {a.x, a.y, a.z, a.w, b.x, b.y, b.z, b.w};
        short8 hv, lv;
#pragma unroll
        for (int j = 0; j < 8; j++) {
            unsigned short hh = f2bf(v[j]);
            hv[j] = (short)hh;
            lv[j] = (short)f2bf(v[j] - bf2f(hh));
        }
        int si = (m << 8) + (d0 ^ ((m & 7) << 3));
        *(short8*)(&tokh[si]) = hv;
        *(short8*)(&tokl[si]) = lv;
    }
    __syncthreads();

    int lane = tid & 63, wid = tid >> 6;   // wid 0..7
    int nb = wid << 5;                     // wave's 32-col N slice
    int arow = lane & 15;
    int kgrp = (lane >> 4) << 3;
    int rb = (lane >> 4) << 2;
    const unsigned short* W1 = w1t + ((size_t)e << 16);
    const unsigned short* W2 = w2t + ((size_t)e << 16);

    f32x4 acc[2][2];
#pragma unroll
    for (int mt = 0; mt < 2; mt++)
#pragma unroll
        for (int nt = 0; nt < 2; nt++) acc[mt][nt] = f32x4{0.f, 0.f, 0.f, 0.f};

#define FFN_KLOOP32(WPTR)                                                                  \
    for (int ks = 0; ks < 8; ks++) {                                                       \
        int kk = (ks << 5) + kgrp;                                                         \
        short8 ah[2], al[2], bw[2];                                                        \
        _Pragma("unroll")                                                                  \
        for (int mt = 0; mt < 2; mt++) {                                                   \
            int m = (mt << 4) + arow;                                                      \
            int si = (m << 8) + (kk ^ ((m & 7) << 3));                                     \
            ah[mt] = *(const short8*)(&tokh[si]);                                          \
            al[mt] = *(const short8*)(&tokl[si]);                                          \
        }                                                                                  \
        _Pragma("unroll")                                                                  \
        for (int nt = 0; nt < 2; nt++)                                                     \
            bw[nt] = *(const short8*)(&WPTR[((size_t)(nb + (nt << 4) + arow) << 8) + kk]); \
        _Pragma("unroll")                                                                  \
        for (int mt = 0; mt < 2; mt++) {                                                   \
            _Pragma("unroll")                                                              \
            for (int nt = 0; nt < 2; nt++) {                                               \
                acc[mt][nt] = __builtin_amdgcn_mfma_f32_16x16x32_bf16(                     \
                    ah[mt], bw[nt], acc[mt][nt], 0, 0, 0);                                 \
                acc[mt][nt] = __builtin_amdgcn_mfma_f32_16x16x32_bf16(                     \
                    al[mt], bw[nt], acc[mt][nt], 0, 0, 0);                                 \
            }                                                                              \
        }                                                                                  \
    }

    // ---- layer 1 ----
    FFN_KLOOP32(W1)

    float b1v[2];
#pragma unroll
    for (int nt = 0; nt < 2; nt++) b1v[nt] = b1[(e << 8) + nb + (nt << 4) + arow];
    __syncthreads();  // all layer-1 LDS reads done before overwrite
#pragma unroll
    for (int mt = 0; mt < 2; mt++) {
#pragma unroll
        for (int nt = 0; nt < 2; nt++) {
            int kd = nb + (nt << 4) + arow;  // output dim -> k-dim of layer 2
#pragma unroll
            for (int r = 0; r < 4; r++) {
                int m = (mt << 4) + rb + r;
                float mid = gelu_f(acc[mt][nt][r] + b1v[nt]);
                unsigned short hh = f2bf(mid);
                int si = (m << 8) + (kd ^ ((m & 7) << 3));
                tokh[si] = hh;
                tokl[si] = f2bf(mid - bf2f(hh));
            }
        }
    }
    __syncthreads();

#pragma unroll
    for (int mt = 0; mt < 2; mt++)
#pragma unroll
        for (int nt = 0; nt < 2; nt++) acc[mt][nt] = f32x4{0.f, 0.f, 0.f, 0.f};

    // ---- layer 2 ----
    FFN_KLOOP32(W2)
#undef FFN_KLOOP32

    float b2v[2];
#pragma unroll
    for (int nt = 0; nt < 2; nt++) b2v[nt] = b2[(e << 8) + nb + (nt << 4) + arow];
#pragma unroll
    for (int mt = 0; mt < 2; mt++) {
        int tt[4]; float tvv[4];
#pragma unroll
        for (int r = 0; r < 4; r++) {
            int m = (mt << 4) + rb + r;
            tt[r] = tids[m];
            tvv[r] = tv[m];
        }
#pragma unroll
        for (int nt = 0; nt < 2; nt++) {
            int n = nb + (nt << 4) + arow;
#pragma unroll
            for (int r = 0; r < 4; r++) {
                int t = tt[r];
                if (t >= 0) {
                    float val = acc[mt][nt][r] + b2v[nt];
                    C[(size_t)t * 256 + n] =
                        xn2[(size_t)t * 256 + n] + val * tvv[r];
                }
            }
        }
    }
}

// ---------------- wave-per-token: A += gelu(rmsnorm(C, moe_gamma)) ----------------
__global__ void moe_add_kernel(const float* __restrict__ C, float* __restrict__ A,
                               const float* __restrict__ gamma, int T) {
    int wid = threadIdx.x >> 6, lane = threadIdx.x & 63;
    int t = blockIdx.x * 4 + wid;
    if (t >= T) return;
    float4 v = ((const float4*)(C + (size_t)t * 256))[lane];
    float ss = v.x * v.x + v.y * v.y + v.z * v.z + v.w * v.w;
    ss = wave_reduce(ss);
    ss = __shfl(ss, 0, 64);
    float inv = 16.0f / fmaxf(sqrtf(ss), 1e-12f);
    float4 g4 = ((const float4*)gamma)[lane];
    float4* ap = (float4*)(A + (size_t)t * 256) + lane;
    float4 a = *ap;
    a.x += gelu_f(v.x * inv * g4.x); a.y += gelu_f(v.y * inv * g4.y);
    a.z += gelu_f(v.z * inv * g4.z); a.w += gelu_f(v.w * inv * g4.w);
    *ap = a;
}

// ---------------- wave-per-token: end-score attn + head dot -> contribution ----------------
__global__ void endhead_kernel(const float* __restrict__ A, const float* __restrict__ w1,
                               const float* __restrict__ b1, const float* __restrict__ w2,
                               const float* __restrict__ b2, const float* __restrict__ hw,
                               const float* __restrict__ hb, float* __restrict__ contrib,
                               int T) {
    int wid = threadIdx.x >> 6, lane = threadIdx.x & 63;
    int t = blockIdx.x * 4 + wid;
    if (t >= T) return;
    float4 v = ((const float4*)(A + (size_t)t * 256))[lane];
    float p[8];
#pragma unroll
    for (int j = 0; j < 8; j++) p[j] = 0.0f;
    const float xv[4] = {v.x, v.y, v.z, v.w};
#pragma unroll
    for (int c = 0; c < 4; c++) {
        const float4* wr = (const float4*)(w1 + (4 * lane + c) * 8);
        float4 wa = wr[0], wb = wr[1];
        float xx = xv[c];
        p[0] += xx * wa.x; p[1] += xx * wa.y; p[2] += xx * wa.z; p[3] += xx * wa.w;
        p[4] += xx * wb.x; p[5] += xx * wb.y; p[6] += xx * wb.z; p[7] += xx * wb.w;
    }
    float4 h4 = ((const float4*)hw)[lane];
    float hp = gelu_f(v.x) * h4.x + gelu_f(v.y) * h4.y + gelu_f(v.z) * h4.z + gelu_f(v.w) * h4.w;
#pragma unroll
    for (int j = 0; j < 8; j++) p[j] = wave_reduce(p[j]);
    hp = wave_reduce(hp);
    if (lane == 0) {
        float z = b2[0];
#pragma unroll
        for (int j = 0; j < 8; j++) z += tanhf(p[j] + b1[j]) * w2[j];
        float sc = 1.0f / (1.0f + expf(-z));
        contrib[t] = (hp + hb[0]) * sc * (1.0f / (float)N1);
    }
}

// ---------------- per-batch sum of contributions + (block 0) load-balance loss --------
__global__ void finalsum_kernel(const float* __restrict__ contrib,
                                const float* __restrict__ imp, float* __restrict__ out) {
    int b = blockIdx.x, tid = threadIdx.x;
    __shared__ float red[4];
    const float* cb = contrib + (size_t)b * N1;
    float v = cb[tid] + cb[256 + tid];
    if (tid == 0) v += cb[512];
    float s = wave_reduce(v);
    int wid = tid >> 6, lane = tid & 63;
    if (lane == 0) red[wid] = s;
    __syncthreads();
    if (tid == 0) {
        out[b] = red[0] + red[1] + red[2] + red[3];
        if (b == 0) {
            float i0 = imp[0], i1 = imp[1], i2 = imp[2], i3 = imp[3];
            float mean = (i0 + i1 + i2 + i3) * 0.25f;
            float var = ((i0 - mean) * (i0 - mean) + (i1 - mean) * (i1 - mean) +
                         (i2 - mean) * (i2 - mean) + (i3 - mean) * (i3 - mean)) / 3.0f;
            out[64] = var / (mean * mean + 1e-10f);
        }
    }
}

extern "C" void kernel_launch(void* const* d_in, const int* in_sizes, int n_in,
                              void* d_out, int out_size, void* d_ws, size_t ws_size,
                              hipStream_t stream) {
    const float* x    = (const float*)d_in[0];
    const float* embw = (const float*)d_in[3];
    const float* embb = (const float*)d_in[4];
    const float* pos  = (const float*)d_in[5];
    const float* aw1  = (const float*)d_in[6];
    const float* ab1  = (const float*)d_in[7];
    const float* aw2  = (const float*)d_in[8];
    const float* ab2  = (const float*)d_in[9];
    const float* gw   = (const float*)d_in[10];
    const float* gb   = (const float*)d_in[11];
    const float* ew1  = (const float*)d_in[12];
    const float* eb1  = (const float*)d_in[13];
    const float* ew2  = (const float*)d_in[14];
    const float* eb2  = (const float*)d_in[15];
    const float* mg   = (const float*)d_in[16];
    const float* n1g  = (const float*)d_in[17];
    const float* n2g  = (const float*)d_in[18];
    const float* bott = (const float*)d_in[19];
    const float* cw39 = (const float*)d_in[20];
    const float* cw19 = (const float*)d_in[21];
    const float* cw9  = (const float*)d_in[22];
    const float* mpw  = (const float*)d_in[23];
    const float* bng  = (const float*)d_in[24];
    const float* bnb  = (const float*)d_in[25];
    const float* pjw  = (const float*)d_in[26];
    const float* pjb  = (const float*)d_in[27];
    const float* hw   = (const float*)d_in[28];
    const float* hb   = (const float*)d_in[29];
    float* out = (float*)d_out;

    float* W = (float*)d_ws;
    size_t off = 0;
    auto alloc = [&](size_t n) { float* p = W + off; off += n; return p; };
    float* A    = alloc((size_t)NTOK0 * 256);
    float* Bb   = alloc((size_t)NTOK0 * 256);
    float* CD   = alloc((size_t)NTOK1 * 256);
    float* XB   = alloc((size_t)NTOK0 * 32);
    float* sS   = alloc(NTOK0);
    float* ctb  = alloc(NTOK1);
    float* tval = alloc(NTOK1);
    float* imp  = alloc(4);
    float* part = alloc((size_t)BB * GCH * 4 * 256);
    off = (off + 3) & ~(size_t)3;  // 16B-align for short8 loads
    unsigned short* w1t  = (unsigned short*)(W + off); off += 262144 / 2;
    unsigned short* w2t  = (unsigned short*)(W + off); off += 262144 / 2;
    unsigned short* pjwb = (unsigned short*)(W + off); off += 65536 / 2;
    unsigned short* cwh  = (unsigned short*)(W + off); off += 137216 / 2;
    unsigned short* cwl  = (unsigned short*)(W + off); off += 137216 / 2;
    unsigned short* ewh  = (unsigned short*)(W + off); off += 32768 / 2;
    unsigned short* ewl  = (unsigned short*)(W + off); off += 32768 / 2;
    unsigned short* bth  = (unsigned short*)(W + off); off += 16384 / 2;
    unsigned short* btl  = (unsigned short*)(W + off); off += 16384 / 2;
    unsigned short* mph  = (unsigned short*)(W + off); off += 16384 / 2;
    unsigned short* mpl  = (unsigned short*)(W + off); off += 16384 / 2;
    int* selpos  = (int*)(W + off); off += (size_t)BB * 1024;
    int* buckets = (int*)(W + off); off += (size_t)4 * NTOK1;
    int* counts  = (int*)(W + off); off += 4;

    convert_bf16<<<3096, 256, 0, stream>>>(ew1, ew2, pjw, cw39, cw19, cw9, embw, bott, mpw,
                                           w1t, w2t, pjwb, cwh, cwl, ewh, ewl,
                                           bth, btl, mph, mpl, imp, counts);

    // ===== layer 0 (N=1023) =====
    embed_mfma<<<dim3(16, BB), 256, 0, stream>>>(x, ewh, ewl, embb, pos, A);
    norm_attn_kernel<<<NTOK0 / 4, 256, 0, stream>>>(A, A, nullptr, n1g, aw1, ab1, aw2, ab2,
                                                    1, 0, Bb, n2g, NTOK0);
    pw_mfma<<<dim3(32, BB), 256, 0, stream>>>(Bb, bth, btl, mph, mpl, bng, bnb, XB, CD, N0);
    conv_mfma<<<dim3(8, BB), 256, 0, stream>>>(XB, cwh, cwl, bng, bnb, CD, N0);
    proj_mfma<<<NTOK0 / 64, 256, 0, stream>>>(CD, pjwb, pjb, A, NTOK0);

    // ===== layer 1 (prune to 513 tokens); gelu fused into load =====
    norm_attn_kernel<<<NTOK0 / 4, 256, 0, stream>>>(A, Bb, sS, n1g + 256, aw1, ab1, aw2, ab2,
                                                    0, 1, nullptr, nullptr, NTOK0);
    topk_kernel<<<BB, 1024, 0, stream>>>(sS, selpos);
    scatter_kernel<<<dim3(GCH, BB), 256, 0, stream>>>(Bb, sS, selpos, A, part);
    extra_kernel<<<BB, 256, 0, stream>>>(part, A);
    rmsnorm_kernel<<<NTOK1 / 4, 256, 0, stream>>>(A, Bb, n2g + 256, NTOK1);
    gate_kernel<<<(NTOK1 + 255) / 256, 256, 0, stream>>>(Bb, gw, gb, tval, buckets, counts, imp,
                                                         NTOK1);
    ffn_kernel<<<dim3((NTOK1 + 31) / 32, 4), 512, 0, stream>>>(Bb, w1t, eb1, w2t, eb2, tval,
                                                               buckets, counts, CD, NTOK1);
    moe_add_kernel<<<NTOK1 / 4, 256, 0, stream>>>(CD, A, mg, NTOK1);
    pw_mfma<<<dim3((N1 + 31) / 32, BB), 256, 0, stream>>>(Bb, bth + 8192, btl + 8192,
                                                          mph + 8192, mpl + 8192,
                                                          bng + 128, bnb + 128, XB, CD, N1);
    conv_mfma<<<dim3((N1 + 127) / 128, BB), 256, 0, stream>>>(XB, cwh + 68608, cwl + 68608,
                                                              bng + 128, bnb + 128, CD, N1);
    proj_mfma<<<NTOK1 / 64, 256, 0, stream>>>(CD, pjwb + 32768, pjb + 256, A, NTOK1);
    endhead_kernel<<<NTOK1 / 4, 256, 0, stream>>>(A, aw1, ab1, aw2, ab2, hw, hb, ctb, NTOK1);
    finalsum_kernel<<<BB, 256, 0, stream>>>(ctb, imp, out);
}

// Round 9
// 733.019 us; speedup vs baseline: 1.2140x; 1.0008x over previous
//
#include <hip/hip_runtime.h>
#include <math.h>

#define BB 64
#define EMB 256
#define N0 1023
#define N1 513
#define NTOK0 (BB * N0)   // 65472
#define NTOK1 (BB * N1)   // 32832
#define GCH 16            // gather chunks per batch

typedef __attribute__((ext_vector_type(8))) short short8;
typedef __attribute__((ext_vector_type(4))) float f32x4;

__device__ __forceinline__ float gelu_f(float x) {
    return 0.5f * x * (1.0f + erff(x * 0.7071067811865476f));
}

__device__ __forceinline__ float4 gelu4(float4 v) {
    return make_float4(gelu_f(v.x), gelu_f(v.y), gelu_f(v.z), gelu_f(v.w));
}

__device__ __forceinline__ float wave_reduce(float v) {
#pragma unroll
    for (int o = 32; o > 0; o >>= 1) v += __shfl_down(v, o, 64);
    return v;
}

// All-lane attn score finish: per-lane partials p[8] -> sigmoid(z) on ALL lanes.
// Grouped butterfly (27 shfl vs 48) + parallel tanh across 8 lanes (vs 8 serial on lane 0).
__device__ __forceinline__ float attn_finish(float p[8], const float* __restrict__ b1,
                                             const float* __restrict__ w2, float b2v,
                                             int lane) {
#pragma unroll
    for (int o = 1; o <= 4; o <<= 1) {
#pragma unroll
        for (int j = 0; j < 8; j++) p[j] += __shfl_xor(p[j], o, 64);
    }
    int j = lane & 7;
    float a0 = (j & 1) ? p[1] : p[0];
    float a1 = (j & 1) ? p[3] : p[2];
    float a2 = (j & 1) ? p[5] : p[4];
    float a3 = (j & 1) ? p[7] : p[6];
    float c0 = (j & 2) ? a1 : a0;
    float c1 = (j & 2) ? a3 : a2;
    float q  = (j & 4) ? c1 : c0;
#pragma unroll
    for (int o = 8; o <= 32; o <<= 1) q += __shfl_xor(q, o, 64);
    float w = tanhf(q + b1[j]) * w2[j];
#pragma unroll
    for (int o = 1; o <= 4; o <<= 1) w += __shfl_xor(w, o, 64);
    float z = w + b2v;
    return 1.0f / (1.0f + expf(-z));
}

// bf16 helpers: pack with round-to-nearest-even; unpack = shift
__device__ __forceinline__ unsigned short f2bf(float f) {
    unsigned int u = __float_as_uint(f);
    u = (u + 0x7FFFu + ((u >> 16) & 1u)) >> 16;
    return (unsigned short)u;
}
__device__ __forceinline__ float bf2f(unsigned short h) {
    return __uint_as_float(((unsigned int)h) << 16);
}

// ---------------- convert weights to bf16 + init imp/counts ----------------
// conv layout per depth d: [branch][fo][k*32+fi]; b39 at 0, b19 at 39936, b9 at 59392.
// bott/mpw: already [d][f][dd] == desired [n][k] B-layout -> direct hi/lo split.
// proj: src [d][k=128][n=256] -> transposed [d][n][k] single bf16.
__global__ void convert_bf16(const float* __restrict__ ew1, const float* __restrict__ ew2,
                             const float* __restrict__ pjw,
                             const float* __restrict__ cw39, const float* __restrict__ cw19,
                             const float* __restrict__ cw9, const float* __restrict__ embw,
                             const float* __restrict__ bott, const float* __restrict__ mpw,
                             unsigned short* __restrict__ w1t, unsigned short* __restrict__ w2t,
                             unsigned short* __restrict__ pjwb,
                             unsigned short* __restrict__ cwh, unsigned short* __restrict__ cwl,
                             unsigned short* __restrict__ ewh, unsigned short* __restrict__ ewl,
                             unsigned short* __restrict__ bth, unsigned short* __restrict__ btl,
                             unsigned short* __restrict__ mph, unsigned short* __restrict__ mpl,
                             float* __restrict__ imp, int* __restrict__ counts) {
    int idx = blockIdx.x * 256 + threadIdx.x;
    if (blockIdx.x == 0 && threadIdx.x >= 252) {
        int i = threadIdx.x - 252;
        imp[i] = 0.0f; counts[i] = 0;
    }
    if (idx < 262144) {
        // out layout [e][n][k]; src [e][k][n]
        int e = idx >> 16, r = idx & 65535, n = r >> 8, k = r & 255;
        w1t[idx] = f2bf(ew1[(e << 16) + (k << 8) + n]);
    } else if (idx < 524288) {
        int j = idx - 262144;
        int e = j >> 16, r = j & 65535, n = r >> 8, k = r & 255;
        w2t[j] = f2bf(ew2[(e << 16) + (k << 8) + n]);
    } else if (idx < 589824) {
        // proj transposed: [d][n][k], src [d][k][n]
        int j = idx - 524288;
        int d = j >> 15, r = j & 32767, n = r >> 7, k = r & 127;
        pjwb[j] = f2bf(pjw[(d << 15) + (k << 8) + n]);
    } else if (idx < 727040) {
        int j = idx - 589824;
        int d = j / 68608, r = j % 68608;
        const float* src; int KT, rr;
        if (r < 39936)      { src = cw39; KT = 39; rr = r; }
        else if (r < 59392) { src = cw19; KT = 19; rr = r - 39936; }
        else                { src = cw9;  KT = 9;  rr = r - 59392; }
        int KK = KT * 32;
        int fo = rr / KK, jj = rr % KK, k = jj >> 5, fi = jj & 31;
        float w = src[(((d * 32 + fo) * 32) + fi) * KT + k];
        unsigned short h = f2bf(w);
        cwh[j] = h;
        cwl[j] = f2bf(w - bf2f(h));
    } else if (idx < 759808) {
        // embw is already [e][k] (k = c*8+s), 256*128
        int j = idx - 727040;
        float w = embw[j];
        unsigned short h = f2bf(w);
        ewh[j] = h;
        ewl[j] = f2bf(w - bf2f(h));
    } else if (idx < 776192) {
        int j = idx - 759808;
        float w = bott[j];
        unsigned short h = f2bf(w);
        bth[j] = h;
        btl[j] = f2bf(w - bf2f(h));
    } else if (idx < 792576) {
        int j = idx - 776192;
        float w = mpw[j];
        unsigned short h = f2bf(w);
        mph[j] = h;
        mpl[j] = f2bf(w - bf2f(h));
    }
}

// ---------------- embedding conv via MFMA: im2col in LDS, hi/lo bf16 ----------------
__global__ __launch_bounds__(256, 2)
void embed_mfma(const float* __restrict__ x, const unsigned short* __restrict__ ewh,
                const unsigned short* __restrict__ ewl, const float* __restrict__ emb_b,
                const float* __restrict__ pos, float* __restrict__ A) {
    int b = blockIdx.y;
    int n0 = blockIdx.x * 64;
    __shared__ __align__(16) unsigned short tokh[64 * 128];  // 16 KB
    __shared__ __align__(16) unsigned short tokl[64 * 128];  // 16 KB
    int tid = threadIdx.x;
#pragma unroll
    for (int it = 0; it < 4; it++) {
        int idx = tid + it * 256;
        int m = idx & 63, c = idx >> 6;
        int tok = n0 + m;
        float v[8] = {0.f, 0.f, 0.f, 0.f, 0.f, 0.f, 0.f, 0.f};
        if (tok < N0) {
            const float* p = x + ((size_t)b * 16 + c) * 4096 + 4 * tok;
            float4 a = *(const float4*)p;
            float4 bq = *(const float4*)(p + 4);
            v[0] = a.x; v[1] = a.y; v[2] = a.z; v[3] = a.w;
            v[4] = bq.x; v[5] = bq.y; v[6] = bq.z; v[7] = bq.w;
        }
        short8 hv, lv;
#pragma unroll
        for (int j = 0; j < 8; j++) {
            unsigned short hh = f2bf(v[j]);
            hv[j] = (short)hh;
            lv[j] = (short)f2bf(v[j] - bf2f(hh));
        }
        int si = (m << 7) + ((c << 3) ^ ((m & 7) << 3));
        *(short8*)(&tokh[si]) = hv;
        *(short8*)(&tokl[si]) = lv;
    }
    __syncthreads();

    int lane = tid & 63, wid = tid >> 6;
    int nb = wid << 6;                 // wave's 64-col emb slice
    int arow = lane & 15;
    int kgrp = (lane >> 4) << 3;
    int rb = (lane >> 4) << 2;

    f32x4 acc[4][4];
#pragma unroll
    for (int mt = 0; mt < 4; mt++)
#pragma unroll
        for (int nt = 0; nt < 4; nt++) acc[mt][nt] = f32x4{0.f, 0.f, 0.f, 0.f};

    for (int ks = 0; ks < 4; ks++) {
        int kk = (ks << 5) + kgrp;
        short8 ah[4], al[4], bh[4], bl[4];
#pragma unroll
        for (int mt = 0; mt < 4; mt++) {
            int m = (mt << 4) + arow;
            int si = (m << 7) + (kk ^ ((m & 7) << 3));
            ah[mt] = *(const short8*)(&tokh[si]);
            al[mt] = *(const short8*)(&tokl[si]);
        }
#pragma unroll
        for (int nt = 0; nt < 4; nt++) {
            int n = nb + (nt << 4) + arow;
            bh[nt] = *(const short8*)(&ewh[(n << 7) + kk]);
            bl[nt] = *(const short8*)(&ewl[(n << 7) + kk]);
        }
#pragma unroll
        for (int mt = 0; mt < 4; mt++) {
#pragma unroll
            for (int nt = 0; nt < 4; nt++) {
                acc[mt][nt] = __builtin_amdgcn_mfma_f32_16x16x32_bf16(ah[mt], bh[nt], acc[mt][nt], 0, 0, 0);
                acc[mt][nt] = __builtin_amdgcn_mfma_f32_16x16x32_bf16(al[mt], bh[nt], acc[mt][nt], 0, 0, 0);
                acc[mt][nt] = __builtin_amdgcn_mfma_f32_16x16x32_bf16(ah[mt], bl[nt], acc[mt][nt], 0, 0, 0);
            }
        }
    }

    float eb[4];
#pragma unroll
    for (int nt = 0; nt < 4; nt++) eb[nt] = emb_b[nb + (nt << 4) + arow];
#pragma unroll
    for (int mt = 0; mt < 4; mt++) {
#pragma unroll
        for (int nt = 0; nt < 4; nt++) {
            int n = nb + (nt << 4) + arow;
#pragma unroll
            for (int r = 0; r < 4; r++) {
                int m = (mt << 4) + rb + r;
                int tok = n0 + m;
                if (tok < N0)
                    A[((size_t)b * N0 + tok) * 256 + n] =
                        acc[mt][nt][r] + eb[nt] + pos[(size_t)tok * 256 + n];
            }
        }
    }
}

// ---------------- wave-per-token: rmsnorm + attn score (+pregelu, +second norm) ------
__global__ void norm_attn_kernel(const float* __restrict__ in, float* __restrict__ outv,
                                 float* __restrict__ score_out, const float* __restrict__ g,
                                 const float* __restrict__ w1, const float* __restrict__ b1,
                                 const float* __restrict__ w2, const float* __restrict__ b2,
                                 int scale_out, int pregelu,
                                 float* __restrict__ outv2, const float* __restrict__ g2,
                                 int T) {
    int wid = threadIdx.x >> 6, lane = threadIdx.x & 63;
    int t = blockIdx.x * 4 + wid;
    if (t >= T) return;
    float4 v = ((const float4*)(in + (size_t)t * 256))[lane];
    if (pregelu) v = gelu4(v);
    float4 xn = v;
    if (g != nullptr) {
        float ss = v.x * v.x + v.y * v.y + v.z * v.z + v.w * v.w;
        ss = wave_reduce(ss);
        ss = __shfl(ss, 0, 64);
        float inv = 16.0f / fmaxf(sqrtf(ss), 1e-12f);
        float4 g4 = ((const float4*)g)[lane];
        xn.x = v.x * inv * g4.x; xn.y = v.y * inv * g4.y;
        xn.z = v.z * inv * g4.z; xn.w = v.w * inv * g4.w;
    }
    float p[8];
#pragma unroll
    for (int j = 0; j < 8; j++) p[j] = 0.0f;
    const float xv[4] = {xn.x, xn.y, xn.z, xn.w};
#pragma unroll
    for (int c = 0; c < 4; c++) {
        const float4* wr = (const float4*)(w1 + (4 * lane + c) * 8);
        float4 wa = wr[0], wb = wr[1];
        float xx = xv[c];
        p[0] += xx * wa.x; p[1] += xx * wa.y; p[2] += xx * wa.z; p[3] += xx * wa.w;
        p[4] += xx * wb.x; p[5] += xx * wb.y; p[6] += xx * wb.z; p[7] += xx * wb.w;
    }
    float sc = attn_finish(p, b1, w2, b2[0], lane);
    if (score_out && lane == 0) score_out[t] = sc;
    if (outv) {
        float m = scale_out ? sc : 1.0f;
        float4 o = make_float4(xn.x * m, xn.y * m, xn.z * m, xn.w * m);
        ((float4*)(outv + (size_t)t * 256))[lane] = o;
    }
    if (outv2) {
        float ss2 = xn.x * xn.x + xn.y * xn.y + xn.z * xn.z + xn.w * xn.w;
        ss2 = wave_reduce(ss2);
        ss2 = __shfl(ss2, 0, 64);
        float inv2 = 16.0f / fmaxf(sqrtf(ss2), 1e-12f);
        float4 q4 = ((const float4*)g2)[lane];
        float4 o;
        o.x = xn.x * inv2 * q4.x; o.y = xn.y * inv2 * q4.y;
        o.z = xn.z * inv2 * q4.z; o.w = xn.w * inv2 * q4.w;
        ((float4*)(outv2 + (size_t)t * 256))[lane] = o;
    }
}

// ---------------- wave-per-token rmsnorm ----------------
__global__ void rmsnorm_kernel(const float* __restrict__ in, float* __restrict__ out,
                               const float* __restrict__ g, int T) {
    int wid = threadIdx.x >> 6, lane = threadIdx.x & 63;
    int t = blockIdx.x * 4 + wid;
    if (t >= T) return;
    float4 v = ((const float4*)(in + (size_t)t * 256))[lane];
    float ss = v.x * v.x + v.y * v.y + v.z * v.z + v.w * v.w;
    ss = wave_reduce(ss);
    ss = __shfl(ss, 0, 64);
    float inv = 16.0f / fmaxf(sqrtf(ss), 1e-12f);
    float4 g4 = ((const float4*)g)[lane];
    float4 o;
    o.x = v.x * inv * g4.x; o.y = v.y * inv * g4.y;
    o.z = v.z * inv * g4.z; o.w = v.w * inv * g4.w;
    ((float4*)(out + (size_t)t * 256))[lane] = o;
}

// ---------------- pointwise bottleneck + maxpool via MFMA, hi/lo bf16 ----------------
__global__ __launch_bounds__(256, 2)
void pw_mfma(const float* __restrict__ xn, const unsigned short* __restrict__ bwh,
             const unsigned short* __restrict__ bwl, const unsigned short* __restrict__ mwh,
             const unsigned short* __restrict__ mwl, const float* __restrict__ bng,
             const float* __restrict__ bnb, float* __restrict__ xb,
             float* __restrict__ cat, int N) {
    int b = blockIdx.y;
    int t0 = blockIdx.x * 32;
    __shared__ __align__(16) unsigned short xth[34 * 256];
    __shared__ __align__(16) unsigned short xtl[34 * 256];
    __shared__ __align__(16) unsigned short xmh[32 * 256];
    __shared__ __align__(16) unsigned short xml[32 * 256];
    const float* xbase = xn + (size_t)b * N * 256;
    int tid = threadIdx.x;
    // stage xt rows (tokens t0-1 .. t0+32), hi/lo, swizzled; OOB = -inf (hi), 0 (lo)
    for (int idx = tid; idx < 34 * 32; idx += 256) {
        int r = idx >> 5, p = (idx & 31) << 3;
        int t = t0 - 1 + r;
        short8 hv, lv;
        if (t >= 0 && t < N) {
            const float4* q = (const float4*)(xbase + (size_t)t * 256 + p);
            float4 a = q[0], c = q[1];
            float v[8] = {a.x, a.y, a.z, a.w, c.x, c.y, c.z, c.w};
#pragma unroll
            for (int j = 0; j < 8; j++) {
                unsigned short hh = f2bf(v[j]);
                hv[j] = (short)hh;
                lv[j] = (short)f2bf(v[j] - bf2f(hh));
            }
        } else {
#pragma unroll
            for (int j = 0; j < 8; j++) { hv[j] = (short)0xFF80; lv[j] = 0; }
        }
        int si = (r << 8) + (p ^ ((r & 7) << 3));
        *(short8*)(&xth[si]) = hv;
        *(short8*)(&xtl[si]) = lv;
    }
    __syncthreads();
    // xm[r] = rowwise max of xt rows r, r+1, r+2 (tokens t-1, t, t+1)
    for (int idx = tid; idx < 32 * 32; idx += 256) {
        int r = idx >> 5, p = (idx & 31) << 3;
        int s0 = ((r + 0) << 8) + (p ^ (((r + 0) & 7) << 3));
        int s1 = ((r + 1) << 8) + (p ^ (((r + 1) & 7) << 3));
        int s2 = ((r + 2) << 8) + (p ^ (((r + 2) & 7) << 3));
        short8 h0 = *(const short8*)(&xth[s0]), l0 = *(const short8*)(&xtl[s0]);
        short8 h1 = *(const short8*)(&xth[s1]), l1 = *(const short8*)(&xtl[s1]);
        short8 h2 = *(const short8*)(&xth[s2]), l2 = *(const short8*)(&xtl[s2]);
        short8 hv, lv;
#pragma unroll
        for (int j = 0; j < 8; j++) {
            float a = bf2f((unsigned short)h0[j]) + bf2f((unsigned short)l0[j]);
            float c = bf2f((unsigned short)h1[j]) + bf2f((unsigned short)l1[j]);
            float d = bf2f((unsigned short)h2[j]) + bf2f((unsigned short)l2[j]);
            float m = fmaxf(fmaxf(a, c), d);
            unsigned short hh = f2bf(m);
            hv[j] = (short)hh;
            lv[j] = (short)f2bf(m - bf2f(hh));
        }
        int si = (r << 8) + (p ^ ((r & 7) << 3));
        *(short8*)(&xmh[si]) = hv;
        *(short8*)(&xml[si]) = lv;
    }
    __syncthreads();

    int lane = tid & 63, wid = tid >> 6;
    int mt = wid & 1, path = wid >> 1;   // path 0 = bottleneck, 1 = maxpool
    int arow = lane & 15, kgrp = (lane >> 4) << 3, rb = (lane >> 4) << 2;
    const unsigned short* Wh = path ? mwh : bwh;
    const unsigned short* Wl = path ? mwl : bwl;
    f32x4 acc[2];
    acc[0] = f32x4{0.f, 0.f, 0.f, 0.f};
    acc[1] = f32x4{0.f, 0.f, 0.f, 0.f};

    int m = (mt << 4) + arow;
    int rowA = path ? m : (m + 1);   // bott reads xt row m+1 (token t0+m); mp reads xm row m
    const unsigned short* Ah = path ? xmh : xth;
    const unsigned short* Al = path ? xml : xtl;
    for (int ks = 0; ks < 8; ks++) {
        int kk = (ks << 5) + kgrp;
        int si = (rowA << 8) + (kk ^ ((rowA & 7) << 3));
        short8 ah = *(const short8*)(&Ah[si]);
        short8 al = *(const short8*)(&Al[si]);
#pragma unroll
        for (int nt = 0; nt < 2; nt++) {
            int n = (nt << 4) + arow;
            short8 bh = *(const short8*)(&Wh[n * 256 + kk]);
            short8 bl = *(const short8*)(&Wl[n * 256 + kk]);
            acc[nt] = __builtin_amdgcn_mfma_f32_16x16x32_bf16(ah, bh, acc[nt], 0, 0, 0);
            acc[nt] = __builtin_amdgcn_mfma_f32_16x16x32_bf16(al, bh, acc[nt], 0, 0, 0);
            acc[nt] = __builtin_amdgcn_mfma_f32_16x16x32_bf16(ah, bl, acc[nt], 0, 0, 0);
        }
    }

    const float BN_DIV = 1.0000050f;
    if (path == 0) {
#pragma unroll
        for (int nt = 0; nt < 2; nt++) {
            int n = (nt << 4) + arow;
#pragma unroll
            for (int r = 0; r < 4; r++) {
                int t = t0 + (mt << 4) + rb + r;
                if (t < N) xb[((size_t)b * N + t) * 32 + n] = acc[nt][r];
            }
        }
    } else {
#pragma unroll
        for (int nt = 0; nt < 2; nt++) {
            int n = (nt << 4) + arow;
            float scl = bng[96 + n] / BN_DIV;
            float sh = bnb[96 + n];
#pragma unroll
            for (int r = 0; r < 4; r++) {
                int t = t0 + (mt << 4) + rb + r;
                if (t < N)
                    cat[((size_t)b * N + t) * 128 + 96 + n] = gelu_f(acc[nt][r] * scl + sh);
            }
        }
    }
}

// ---------------- inception time-convs via MFMA, split hi/lo bf16 ----------------
// Block: 128 output tokens (4 waves x 2 m-tiles x 16), all 3 branches, 32 fo each.
__global__ __launch_bounds__(256, 2)
void conv_mfma(const float* __restrict__ xb, const unsigned short* __restrict__ wh,
               const unsigned short* __restrict__ wl, const float* __restrict__ bng,
               const float* __restrict__ bnb, float* __restrict__ cat, int N) {
    int b = blockIdx.y;
    int t0 = blockIdx.x * 128;
    __shared__ __align__(16) unsigned short tokh[167 * 32];
    __shared__ __align__(16) unsigned short tokl[167 * 32];
    const float* xbase = xb + (size_t)b * N * 32;
    int tid = threadIdx.x;
    for (int idx = tid; idx < 167 * 16; idx += 256) {
        int r = idx >> 4, c = (idx & 15) << 1;
        int t = t0 - 19 + r;
        float vx = 0.f, vy = 0.f;
        if (t >= 0 && t < N) {
            const float2 v = *(const float2*)(xbase + (size_t)t * 32 + c);
            vx = v.x; vy = v.y;
        }
        unsigned short h0 = f2bf(vx), h1 = f2bf(vy);
        unsigned short l0 = f2bf(vx - bf2f(h0)), l1 = f2bf(vy - bf2f(h1));
        int si = (r << 5) + ((((c >> 3) ^ ((r >> 1) & 3)) << 3) | (c & 7));
        *(unsigned int*)(&tokh[si]) = (unsigned)h0 | ((unsigned)h1 << 16);
        *(unsigned int*)(&tokl[si]) = (unsigned)l0 | ((unsigned)l1 << 16);
    }
    __syncthreads();
    int lane = tid & 63, wid = tid >> 6;
    int arow = lane & 15, g = lane >> 4, kgrp = g << 3;
    int rb = g << 2;
    f32x4 acc[3][2][2];
#pragma unroll
    for (int i = 0; i < 3; i++)
#pragma unroll
        for (int m = 0; m < 2; m++) {
            acc[i][m][0] = f32x4{0.f, 0.f, 0.f, 0.f};
            acc[i][m][1] = f32x4{0.f, 0.f, 0.f, 0.f};
        }

#define SIA(row) (((row) << 5) + ((g ^ (((row) >> 1) & 3)) << 3))
#define CONV_BR(KT, BOFF, WOFF, BR)                                                        \
    {                                                                                      \
        const int KK = (KT) * 32;                                                          \
        int r0 = (WOFF) + wid * 32 + arow;                                                 \
        const unsigned short* whp = wh + (BOFF) + arow * KK + kgrp;                        \
        const unsigned short* wlp = wl + (BOFF) + arow * KK + kgrp;                        \
        for (int k = 0; k < (KT); k++) {                                                   \
            int ra = r0 + k, rc = r0 + 16 + k;                                             \
            short8 ah0 = *(const short8*)(&tokh[SIA(ra)]);                                 \
            short8 al0 = *(const short8*)(&tokl[SIA(ra)]);                                 \
            short8 ah1 = *(const short8*)(&tokh[SIA(rc)]);                                 \
            short8 al1 = *(const short8*)(&tokl[SIA(rc)]);                                 \
            short8 bh0 = *(const short8*)(&whp[k * 32]);                                   \
            short8 bl0 = *(const short8*)(&wlp[k * 32]);                                   \
            short8 bh1 = *(const short8*)(&whp[16 * KK + k * 32]);                         \
            short8 bl1 = *(const short8*)(&wlp[16 * KK + k * 32]);                         \
            acc[BR][0][0] = __builtin_amdgcn_mfma_f32_16x16x32_bf16(ah0, bh0, acc[BR][0][0], 0, 0, 0); \
            acc[BR][0][1] = __builtin_amdgcn_mfma_f32_16x16x32_bf16(ah0, bh1, acc[BR][0][1], 0, 0, 0); \
            acc[BR][0][0] = __builtin_amdgcn_mfma_f32_16x16x32_bf16(al0, bh0, acc[BR][0][0], 0, 0, 0); \
            acc[BR][0][1] = __builtin_amdgcn_mfma_f32_16x16x32_bf16(al0, bh1, acc[BR][0][1], 0, 0, 0); \
            acc[BR][0][0] = __builtin_amdgcn_mfma_f32_16x16x32_bf16(ah0, bl0, acc[BR][0][0], 0, 0, 0); \
            acc[BR][0][1] = __builtin_amdgcn_mfma_f32_16x16x32_bf16(ah0, bl1, acc[BR][0][1], 0, 0, 0); \
            acc[BR][1][0] = __builtin_amdgcn_mfma_f32_16x16x32_bf16(ah1, bh0, acc[BR][1][0], 0, 0, 0); \
            acc[BR][1][1] = __builtin_amdgcn_mfma_f32_16x16x32_bf16(ah1, bh1, acc[BR][1][1], 0, 0, 0); \
            acc[BR][1][0] = __builtin_amdgcn_mfma_f32_16x16x32_bf16(al1, bh0, acc[BR][1][0], 0, 0, 0); \
            acc[BR][1][1] = __builtin_amdgcn_mfma_f32_16x16x32_bf16(al1, bh1, acc[BR][1][1], 0, 0, 0); \
            acc[BR][1][0] = __builtin_amdgcn_mfma_f32_16x16x32_bf16(ah1, bl0, acc[BR][1][0], 0, 0, 0); \
            acc[BR][1][1] = __builtin_amdgcn_mfma_f32_16x16x32_bf16(ah1, bl1, acc[BR][1][1], 0, 0, 0); \
        }                                                                                  \
    }

    CONV_BR(39, 0, 0, 0)
    CONV_BR(19, 39936, 10, 1)
    CONV_BR(9, 59392, 15, 2)
#undef CONV_BR
#undef SIA

    const float BN_DIV = 1.0000050f;
    const int COFFS[3] = {0, 32, 64};
#pragma unroll
    for (int br = 0; br < 3; br++) {
#pragma unroll
        for (int mt = 0; mt < 2; mt++) {
#pragma unroll
            for (int nt = 0; nt < 2; nt++) {
                int fo = COFFS[br] + nt * 16 + arow;
                float scl = bng[fo] / BN_DIV;
                float sh = bnb[fo];
#pragma unroll
                for (int r = 0; r < 4; r++) {
                    int t = t0 + wid * 32 + mt * 16 + rb + r;
                    if (t < N)
                        cat[((size_t)b * N + t) * 128 + fo] =
                            gelu_f(acc[br][mt][nt][r] * scl + sh);
                }
            }
        }
    }
}

// ---------------- proj via MFMA: K=128, hi/lo bf16 activations, bf16 weights ----------
__global__ __launch_bounds__(256, 2)
void proj_mfma(const float* __restrict__ cat, const unsigned short* __restrict__ pjt,
               const float* __restrict__ pb, float* __restrict__ A, int TN) {
    int t0 = blockIdx.x * 64;
    __shared__ __align__(16) unsigned short tokh[64 * 128];  // 16 KB
    __shared__ __align__(16) unsigned short tokl[64 * 128];  // 16 KB
    int tid = threadIdx.x;
#pragma unroll
    for (int it = 0; it < 4; it++) {
        int idx = tid + it * 256;
        int m = idx >> 4, c = idx & 15;
        int t = t0 + m;
        float v[8] = {0.f, 0.f, 0.f, 0.f, 0.f, 0.f, 0.f, 0.f};
        if (t < TN) {
            const float4* q = (const float4*)(cat + (size_t)t * 128 + (c << 3));
            float4 a = q[0], bq = q[1];
            v[0] = a.x; v[1] = a.y; v[2] = a.z; v[3] = a.w;
            v[4] = bq.x; v[5] = bq.y; v[6] = bq.z; v[7] = bq.w;
        }
        short8 hv, lv;
#pragma unroll
        for (int j = 0; j < 8; j++) {
            unsigned short hh = f2bf(v[j]);
            hv[j] = (short)hh;
            lv[j] = (short)f2bf(v[j] - bf2f(hh));
        }
        int si = (m << 7) + ((c << 3) ^ ((m & 7) << 3));
        *(short8*)(&tokh[si]) = hv;
        *(short8*)(&tokl[si]) = lv;
    }
    __syncthreads();

    int lane = tid & 63, wid = tid >> 6;
    int nb = wid << 6;
    int arow = lane & 15;
    int kgrp = (lane >> 4) << 3;
    int rb = (lane >> 4) << 2;

    f32x4 acc[4][4];
#pragma unroll
    for (int mt = 0; mt < 4; mt++)
#pragma unroll
        for (int nt = 0; nt < 4; nt++) acc[mt][nt] = f32x4{0.f, 0.f, 0.f, 0.f};

    for (int ks = 0; ks < 4; ks++) {
        int kk = (ks << 5) + kgrp;
        short8 ah[4], al[4], bw[4];
#pragma unroll
        for (int mt = 0; mt < 4; mt++) {
            int m = (mt << 4) + arow;
            int si = (m << 7) + (kk ^ ((m & 7) << 3));
            ah[mt] = *(const short8*)(&tokh[si]);
            al[mt] = *(const short8*)(&tokl[si]);
        }
#pragma unroll
        for (int nt = 0; nt < 4; nt++) {
            int n = nb + (nt << 4) + arow;
            bw[nt] = *(const short8*)(&pjt[(n << 7) + kk]);
        }
#pragma unroll
        for (int mt = 0; mt < 4; mt++) {
#pragma unroll
            for (int nt = 0; nt < 4; nt++) {
                acc[mt][nt] = __builtin_amdgcn_mfma_f32_16x16x32_bf16(ah[mt], bw[nt], acc[mt][nt], 0, 0, 0);
                acc[mt][nt] = __builtin_amdgcn_mfma_f32_16x16x32_bf16(al[mt], bw[nt], acc[mt][nt], 0, 0, 0);
            }
        }
    }

    float bias[4];
#pragma unroll
    for (int nt = 0; nt < 4; nt++) bias[nt] = pb[nb + (nt << 4) + arow];
#pragma unroll
    for (int mt = 0; mt < 4; mt++) {
#pragma unroll
        for (int nt = 0; nt < 4; nt++) {
            int n = nb + (nt << 4) + arow;
#pragma unroll
            for (int r = 0; r < 4; r++) {
                int t = t0 + (mt << 4) + rb + r;
                if (t < TN) {
                    float* ap = A + (size_t)t * 256 + n;
                    *ap += acc[mt][nt][r] + bias[nt];
                }
            }
        }
    }
}

// ---------------- top-512-of-1023 per batch ----------------
__global__ __launch_bounds__(1024) void topk_kernel(const float* __restrict__ s,
                                                    int* __restrict__ selpos) {
    int b = blockIdx.x;
    int tid = threadIdx.x;
    __shared__ float srt[1024];
    __shared__ int buf[1024];
    __shared__ int Gtot_s;
    float val = (tid < N0) ? s[(size_t)b * N0 + tid] : -INFINITY;
    srt[tid] = val;
    __syncthreads();
    for (int ksz = 2; ksz <= 1024; ksz <<= 1) {
        for (int j = ksz >> 1; j > 0; j >>= 1) {
            int ixj = tid ^ j;
            if (ixj > tid) {
                float a = srt[tid], c = srt[ixj];
                bool up = ((tid & ksz) == 0);
                if ((a > c) == up) { srt[tid] = c; srt[ixj] = a; }
            }
            __syncthreads();
        }
    }
    float thr = srt[512];
    __syncthreads();
    int isG = (val > thr) ? 1 : 0;
    int isE = (val == thr) ? 1 : 0;
    buf[tid] = isG;
    __syncthreads();
    for (int off = 1; off < 1024; off <<= 1) {
        int cur = buf[tid];
        int add = (tid >= off) ? buf[tid - off] : 0;
        __syncthreads();
        buf[tid] = cur + add;
        __syncthreads();
    }
    if (tid == 0) Gtot_s = buf[1023];
    __syncthreads();
    int Gtot = Gtot_s;
    int Eneed = 512 - Gtot;
    buf[tid] = isE;
    __syncthreads();
    for (int off = 1; off < 1024; off <<= 1) {
        int cur = buf[tid];
        int add = (tid >= off) ? buf[tid - off] : 0;
        __syncthreads();
        buf[tid] = cur + add;
        __syncthreads();
    }
    int eqExcl = buf[tid] - isE;
    int sel = (isG || (isE && eqExcl < Eneed)) ? 1 : 0;
    __syncthreads();
    buf[tid] = sel;
    __syncthreads();
    for (int off = 1; off < 1024; off <<= 1) {
        int cur = buf[tid];
        int add = (tid >= off) ? buf[tid - off] : 0;
        __syncthreads();
        buf[tid] = cur + add;
        __syncthreads();
    }
    int pos = buf[tid] - sel;
    selpos[b * 1024 + tid] = sel ? pos : -1;
}

// ---------------- scatter: 4 token-groups x float4; 4 partials per chunk ----------------
__global__ void scatter_kernel(const float* __restrict__ xn, const float* __restrict__ s,
                               const int* __restrict__ selpos, float* __restrict__ A,
                               float* __restrict__ part) {
    int b = blockIdx.y;
    int chunk = blockIdx.x;
    int wid = threadIdx.x >> 6, lane = threadIdx.x & 63;
    int t0 = chunk * 64;
    __shared__ float sl[64];
    __shared__ int pl[64];
    if (threadIdx.x < 64) {
        int t = t0 + threadIdx.x;
        sl[threadIdx.x] = (t < N0) ? s[(size_t)b * N0 + t] : 0.0f;
        pl[threadIdx.x] = (t < N0) ? selpos[b * 1024 + t] : -1;
    }
    __syncthreads();
    const float* xbase = xn + ((size_t)b * N0 + t0) * 256;
    float* obase = A + (size_t)b * N1 * 256;
    float4 nonsel = make_float4(0.f, 0.f, 0.f, 0.f);
    int tmax = (t0 + 64 <= N0) ? 64 : (N0 - t0);
    for (int i = wid; i < tmax; i += 4) {
        float sc = sl[i];
        float4 v = ((const float4*)(xbase + (size_t)i * 256))[lane];
        v.x *= sc; v.y *= sc; v.z *= sc; v.w *= sc;
        int p = pl[i];
        if (p >= 0) ((float4*)(obase + (size_t)p * 256))[lane] = v;
        else { nonsel.x += v.x; nonsel.y += v.y; nonsel.z += v.z; nonsel.w += v.w; }
    }
    ((float4*)(part + ((size_t)(b * GCH + chunk) * 4 + wid) * 256))[lane] = nonsel;
}

// ---------------- reduce chunk partials (64 per batch) -> extra row ----------------
__global__ void extra_kernel(const float* __restrict__ part, float* __restrict__ A) {
    int b = blockIdx.x, d = threadIdx.x;
    float acc = 0.0f;
    for (int c = 0; c < GCH * 4; c++) acc += part[((size_t)b * GCH * 4 + c) * 256 + d];
    A[((size_t)b * N1 + 512) * 256 + d] = acc;
}

// ---------------- gate: one token per thread, block-aggregated routing ----------------
__global__ void gate_kernel(const float* __restrict__ xn2, const float* __restrict__ gw,
                            const float* __restrict__ gb, float* __restrict__ topval,
                            int* __restrict__ buckets, int* __restrict__ counts,
                            float* __restrict__ imp, int T) {
    int tid = threadIdx.x;
    int t = blockIdx.x * 256 + tid;
    __shared__ float4 gws[256];
    __shared__ int lcount[4];
    __shared__ int lbase[4];
    __shared__ float limp[4];
    gws[tid] = ((const float4*)gw)[tid];
    if (tid < 4) { lcount[tid] = 0; limp[tid] = 0.0f; }
    __syncthreads();
    bool valid = (t < T);
    float a0 = 0, a1 = 0, a2 = 0, a3 = 0;
    if (valid) {
        const float4* xb4 = (const float4*)(xn2 + (size_t)t * 256);
#pragma unroll 8
        for (int d4 = 0; d4 < 64; d4++) {
            float4 xv = xb4[d4];
            float4 w0 = gws[4 * d4], w1 = gws[4 * d4 + 1];
            float4 w2 = gws[4 * d4 + 2], w3 = gws[4 * d4 + 3];
            a0 += xv.x * w0.x + xv.y * w1.x + xv.z * w2.x + xv.w * w3.x;
            a1 += xv.x * w0.y + xv.y * w1.y + xv.z * w2.y + xv.w * w3.y;
            a2 += xv.x * w0.z + xv.y * w1.z + xv.z * w2.z + xv.w * w3.z;
            a3 += xv.x * w0.w + xv.y * w1.w + xv.z * w2.w + xv.w * w3.w;
        }
    }
    float q0 = 0, q1 = 0, q2 = 0, q3 = 0;
    int eid = 0;
    int lrank = 0;
    if (valid) {
        float l0 = a0 + gb[0], l1 = a1 + gb[1], l2 = a2 + gb[2], l3 = a3 + gb[3];
        float m = fmaxf(fmaxf(l0, l1), fmaxf(l2, l3));
        float e0 = expf(l0 - m), e1 = expf(l1 - m), e2 = expf(l2 - m), e3 = expf(l3 - m);
        float ssum = e0 + e1 + e2 + e3;
        q0 = e0 / ssum; q1 = e1 / ssum; q2 = e2 / ssum; q3 = e3 / ssum;
        float bv = q0;
        if (q1 > bv) { bv = q1; eid = 1; }
        if (q2 > bv) { bv = q2; eid = 2; }
        if (q3 > bv) { bv = q3; eid = 3; }
        topval[t] = bv;
        lrank = atomicAdd(&lcount[eid], 1);
    }
    float r0 = wave_reduce(q0), r1 = wave_reduce(q1);
    float r2 = wave_reduce(q2), r3 = wave_reduce(q3);
    if ((tid & 63) == 0) {
        atomicAdd(&limp[0], r0); atomicAdd(&limp[1], r1);
        atomicAdd(&limp[2], r2); atomicAdd(&limp[3], r3);
    }
    __syncthreads();
    if (tid < 4) {
        lbase[tid] = atomicAdd(&counts[tid], lcount[tid]);
        atomicAdd(&imp[tid], limp[tid]);
    }
    __syncthreads();
    if (valid) buckets[eid * T + lbase[eid] + lrank] = t;
}

// ---------------- expert FFN: MFMA bf16, split hi/lo activations ----------------
// 32-token tile, 8 waves (512 thr), 32.3 KB LDS -> 4 blocks/CU = 32 waves/CU (100% cap).
__global__ __launch_bounds__(512, 1)
void ffn_kernel(const float* __restrict__ xn2, const unsigned short* __restrict__ w1t,
                const float* __restrict__ b1, const unsigned short* __restrict__ w2t,
                const float* __restrict__ b2, const float* __restrict__ topval,
                const int* __restrict__ buckets, const int* __restrict__ counts,
                float* __restrict__ C, int T) {
    int e = blockIdx.y;
    int cnt = counts[e];
    int base = blockIdx.x * 32;
    if (base >= cnt) return;
    __shared__ __align__(16) unsigned short tokh[32 * 256];  // 16 KB
    __shared__ __align__(16) unsigned short tokl[32 * 256];  // 16 KB
    __shared__ int tids[32];
    __shared__ float tv[32];
    int tid = threadIdx.x;
    if (tid < 32) {
        int idx = base + tid;
        int t = (idx < cnt) ? buckets[e * T + idx] : -1;
        tids[tid] = t;
        tv[tid] = (t >= 0) ? topval[t] : 0.0f;
    }
    __syncthreads();
#pragma unroll
    for (int it = 0; it < 2; it++) {
        int cc = tid + it * 512;
        int m = cc >> 5, d0 = (cc & 31) << 3;
        int t = tids[m];
        float4 a = make_float4(0.f, 0.f, 0.f, 0.f), b = a;
        if (t >= 0) {
            const float4* p = (const float4*)(xn2 + (size_t)t * 256 + d0);
            a = p[0]; b = p[1];
        }
        float v[8] = {a.x, a.y, a.z, a.w, b.x, b.y, b.z, b.w};
        short8 hv, lv;
#pragma unroll
        for (int j = 0; j < 8; j++) {
            unsigned short hh = f2bf(v[j]);
            hv[j] = (short)hh;
            lv[j] = (short)f2bf(v[j] - bf2f(hh));
        }
        int si = (m << 8) + (d0 ^ ((m & 7) << 3));
        *(short8*)(&tokh[si]) = hv;
        *(short8*)(&tokl[si]) = lv;
    }
    __syncthreads();

    int lane = tid & 63, wid = tid >> 6;   // wid 0..7
    int nb = wid << 5;                     // wave's 32-col N slice
    int arow = lane & 15;
    int kgrp = (lane >> 4) << 3;
    int rb = (lane >> 4) << 2;
    const unsigned short* W1 = w1t + ((size_t)e << 16);
    const unsigned short* W2 = w2t + ((size_t)e << 16);

    f32x4 acc[2][2];
#pragma unroll
    for (int mt = 0; mt < 2; mt++)
#pragma unroll
        for (int nt = 0; nt < 2; nt++) acc[mt][nt] = f32x4{0.f, 0.f, 0.f, 0.f};

#define FFN_KLOOP32(WPTR)                                                                  \
    for (int ks = 0; ks < 8; ks++) {                                                       \
        int kk = (ks << 5) + kgrp;                                                         \
        short8 ah[2], al[2], bw[2];                                                        \
        _Pragma("unroll")                                                                  \
        for (int mt = 0; mt < 2; mt++) {                                                   \
            int m = (mt << 4) + arow;                                                      \
            int si = (m << 8) + (kk ^ ((m & 7) << 3));                                     \
            ah[mt] = *(const short8*)(&tokh[si]);                                          \
            al[mt] = *(const short8*)(&tokl[si]);                                          \
        }                                                                                  \
        _Pragma("unroll")                                                                  \
        for (int nt = 0; nt < 2; nt++)                                                     \
            bw[nt] = *(const short8*)(&WPTR[((size_t)(nb + (nt << 4) + arow) << 8) + kk]); \
        _Pragma("unroll")                                                                  \
        for (int mt = 0; mt < 2; mt++) {                                                   \
            _Pragma("unroll")                                                              \
            for (int nt = 0; nt < 2; nt++) {                                               \
                acc[mt][nt] = __builtin_amdgcn_mfma_f32_16x16x32_bf16(                     \
                    ah[mt], bw[nt], acc[mt][nt], 0, 0, 0);                                 \
                acc[mt][nt] = __builtin_amdgcn_mfma_f32_16x16x32_bf16(                     \
                    al[mt], bw[nt], acc[mt][nt], 0, 0, 0);                                 \
            }                                                                              \
        }                                                                                  \
    }

    // ---- layer 1 ----
    FFN_KLOOP32(W1)

    float b1v[2];
#pragma unroll
    for (int nt = 0; nt < 2; nt++) b1v[nt] = b1[(e << 8) + nb + (nt << 4) + arow];
    __syncthreads();  // all layer-1 LDS reads done before overwrite
#pragma unroll
    for (int mt = 0; mt < 2; mt++) {
#pragma unroll
        for (int nt = 0; nt < 2; nt++) {
            int kd = nb + (nt << 4) + arow;  // output dim -> k-dim of layer 2
#pragma unroll
            for (int r = 0; r < 4; r++) {
                int m = (mt << 4) + rb + r;
                float mid = gelu_f(acc[mt][nt][r] + b1v[nt]);
                unsigned short hh = f2bf(mid);
                int si = (m << 8) + (kd ^ ((m & 7) << 3));
                tokh[si] = hh;
                tokl[si] = f2bf(mid - bf2f(hh));
            }
        }
    }
    __syncthreads();

#pragma unroll
    for (int mt = 0; mt < 2; mt++)
#pragma unroll
        for (int nt = 0; nt < 2; nt++) acc[mt][nt] = f32x4{0.f, 0.f, 0.f, 0.f};

    // ---- layer 2 ----
    FFN_KLOOP32(W2)
#undef FFN_KLOOP32

    float b2v[2];
#pragma unroll
    for (int nt = 0; nt < 2; nt++) b2v[nt] = b2[(e << 8) + nb + (nt << 4) + arow];
#pragma unroll
    for (int mt = 0; mt < 2; mt++) {
        int tt[4]; float tvv[4];
#pragma unroll
        for (int r = 0; r < 4; r++) {
            int m = (mt << 4) + rb + r;
            tt[r] = tids[m];
            tvv[r] = tv[m];
        }
#pragma unroll
        for (int nt = 0; nt < 2; nt++) {
            int n = nb + (nt << 4) + arow;
#pragma unroll
            for (int r = 0; r < 4; r++) {
                int t = tt[r];
                if (t >= 0) {
                    float val = acc[mt][nt][r] + b2v[nt];
                    C[(size_t)t * 256 + n] =
                        xn2[(size_t)t * 256 + n] + val * tvv[r];
                }
            }
        }
    }
}

// ---------------- wave-per-token: A += gelu(rmsnorm(C, moe_gamma)) ----------------
__global__ void moe_add_kernel(const float* __restrict__ C, float* __restrict__ A,
                               const float* __restrict__ gamma, int T) {
    int wid = threadIdx.x >> 6, lane = threadIdx.x & 63;
    int t = blockIdx.x * 4 + wid;
    if (t >= T) return;
    float4 v = ((const float4*)(C + (size_t)t * 256))[lane];
    float ss = v.x * v.x + v.y * v.y + v.z * v.z + v.w * v.w;
    ss = wave_reduce(ss);
    ss = __shfl(ss, 0, 64);
    float inv = 16.0f / fmaxf(sqrtf(ss), 1e-12f);
    float4 g4 = ((const float4*)gamma)[lane];
    float4* ap = (float4*)(A + (size_t)t * 256) + lane;
    float4 a = *ap;
    a.x += gelu_f(v.x * inv * g4.x); a.y += gelu_f(v.y * inv * g4.y);
    a.z += gelu_f(v.z * inv * g4.z); a.w += gelu_f(v.w * inv * g4.w);
    *ap = a;
}

// ---------------- wave-per-token: end-score attn + head dot -> contribution ----------------
__global__ void endhead_kernel(const float* __restrict__ A, const float* __restrict__ w1,
                               const float* __restrict__ b1, const float* __restrict__ w2,
                               const float* __restrict__ b2, const float* __restrict__ hw,
                               const float* __restrict__ hb, float* __restrict__ contrib,
                               int T) {
    int wid = threadIdx.x >> 6, lane = threadIdx.x & 63;
    int t = blockIdx.x * 4 + wid;
    if (t >= T) return;
    float4 v = ((const float4*)(A + (size_t)t * 256))[lane];
    float p[8];
#pragma unroll
    for (int j = 0; j < 8; j++) p[j] = 0.0f;
    const float xv[4] = {v.x, v.y, v.z, v.w};
#pragma unroll
    for (int c = 0; c < 4; c++) {
        const float4* wr = (const float4*)(w1 + (4 * lane + c) * 8);
        float4 wa = wr[0], wb = wr[1];
        float xx = xv[c];
        p[0] += xx * wa.x; p[1] += xx * wa.y; p[2] += xx * wa.z; p[3] += xx * wa.w;
        p[4] += xx * wb.x; p[5] += xx * wb.y; p[6] += xx * wb.z; p[7] += xx * wb.w;
    }
    float4 h4 = ((const float4*)hw)[lane];
    float hp = gelu_f(v.x) * h4.x + gelu_f(v.y) * h4.y + gelu_f(v.z) * h4.z + gelu_f(v.w) * h4.w;
    hp = wave_reduce(hp);
    float sc = attn_finish(p, b1, w2, b2[0], lane);
    if (lane == 0) {
        contrib[t] = (hp + hb[0]) * sc * (1.0f / (float)N1);
    }
}

// ---------------- per-batch sum of contributions + (block 0) load-balance loss --------
__global__ void finalsum_kernel(const float* __restrict__ contrib,
                                const float* __restrict__ imp, float* __restrict__ out) {
    int b = blockIdx.x, tid = threadIdx.x;
    __shared__ float red[4];
    const float* cb = contrib + (size_t)b * N1;
    float v = cb[tid] + cb[256 + tid];
    if (tid == 0) v += cb[512];
    float s = wave_reduce(v);
    int wid = tid >> 6, lane = tid & 63;
    if (lane == 0) red[wid] = s;
    __syncthreads();
    if (tid == 0) {
        out[b] = red[0] + red[1] + red[2] + red[3];
        if (b == 0) {
            float i0 = imp[0], i1 = imp[1], i2 = imp[2], i3 = imp[3];
            float mean = (i0 + i1 + i2 + i3) * 0.25f;
            float var = ((i0 - mean) * (i0 - mean) + (i1 - mean) * (i1 - mean) +
                         (i2 - mean) * (i2 - mean) + (i3 - mean) * (i3 - mean)) / 3.0f;
            out[64] = var / (mean * mean + 1e-10f);
        }
    }
}

extern "C" void kernel_launch(void* const* d_in, const int* in_sizes, int n_in,
                              void* d_out, int out_size, void* d_ws, size_t ws_size,
                              hipStream_t stream) {
    const float* x    = (const float*)d_in[0];
    const float* embw = (const float*)d_in[3];
    const float* embb = (const float*)d_in[4];
    const float* pos  = (const float*)d_in[5];
    const float* aw1  = (const float*)d_in[6];
    const float* ab1  = (const float*)d_in[7];
    const float* aw2  = (const float*)d_in[8];
    const float* ab2  = (const float*)d_in[9];
    const float* gw   = (const float*)d_in[10];
    const float* gb   = (const float*)d_in[11];
    const float* ew1  = (const float*)d_in[12];
    const float* eb1  = (const float*)d_in[13];
    const float* ew2  = (const float*)d_in[14];
    const float* eb2  = (const float*)d_in[15];
    const float* mg   = (const float*)d_in[16];
    const float* n1g  = (const float*)d_in[17];
    const float* n2g  = (const float*)d_in[18];
    const float* bott = (const float*)d_in[19];
    const float* cw39 = (const float*)d_in[20];
    const float* cw19 = (const float*)d_in[21];
    const float* cw9  = (const float*)d_in[22];
    const float* mpw  = (const float*)d_in[23];
    const float* bng  = (const float*)d_in[24];
    const float* bnb  = (const float*)d_in[25];
    const float* pjw  = (const float*)d_in[26];
    const float* pjb  = (const float*)d_in[27];
    const float* hw   = (const float*)d_in[28];
    const float* hb   = (const float*)d_in[29];
    float* out = (float*)d_out;

    float* W = (float*)d_ws;
    size_t off = 0;
    auto alloc = [&](size_t n) { float* p = W + off; off += n; return p; };
    float* A    = alloc((size_t)NTOK0 * 256);
    float* Bb   = alloc((size_t)NTOK0 * 256);
    float* CD   = alloc((size_t)NTOK1 * 256);
    float* XB   = alloc((size_t)NTOK0 * 32);
    float* sS   = alloc(NTOK0);
    float* ctb  = alloc(NTOK1);
    float* tval = alloc(NTOK1);
    float* imp  = alloc(4);
    float* part = alloc((size_t)BB * GCH * 4 * 256);
    off = (off + 3) & ~(size_t)3;  // 16B-align for short8 loads
    unsigned short* w1t  = (unsigned short*)(W + off); off += 262144 / 2;
    unsigned short* w2t  = (unsigned short*)(W + off); off += 262144 / 2;
    unsigned short* pjwb = (unsigned short*)(W + off); off += 65536 / 2;
    unsigned short* cwh  = (unsigned short*)(W + off); off += 137216 / 2;
    unsigned short* cwl  = (unsigned short*)(W + off); off += 137216 / 2;
    unsigned short* ewh  = (unsigned short*)(W + off); off += 32768 / 2;
    unsigned short* ewl  = (unsigned short*)(W + off); off += 32768 / 2;
    unsigned short* bth  = (unsigned short*)(W + off); off += 16384 / 2;
    unsigned short* btl  = (unsigned short*)(W + off); off += 16384 / 2;
    unsigned short* mph  = (unsigned short*)(W + off); off += 16384 / 2;
    unsigned short* mpl  = (unsigned short*)(W + off); off += 16384 / 2;
    int* selpos  = (int*)(W + off); off += (size_t)BB * 1024;
    int* buckets = (int*)(W + off); off += (size_t)4 * NTOK1;
    int* counts  = (int*)(W + off); off += 4;

    convert_bf16<<<3096, 256, 0, stream>>>(ew1, ew2, pjw, cw39, cw19, cw9, embw, bott, mpw,
                                           w1t, w2t, pjwb, cwh, cwl, ewh, ewl,
                                           bth, btl, mph, mpl, imp, counts);

    // ===== layer 0 (N=1023) =====
    embed_mfma<<<dim3(16, BB), 256, 0, stream>>>(x, ewh, ewl, embb, pos, A);
    norm_attn_kernel<<<NTOK0 / 4, 256, 0, stream>>>(A, A, nullptr, n1g, aw1, ab1, aw2, ab2,
                                                    1, 0, Bb, n2g, NTOK0);
    pw_mfma<<<dim3(32, BB), 256, 0, stream>>>(Bb, bth, btl, mph, mpl, bng, bnb, XB, CD, N0);
    conv_mfma<<<dim3(8, BB), 256, 0, stream>>>(XB, cwh, cwl, bng, bnb, CD, N0);
    proj_mfma<<<NTOK0 / 64, 256, 0, stream>>>(CD, pjwb, pjb, A, NTOK0);

    // ===== layer 1 (prune to 513 tokens); gelu fused into load =====
    norm_attn_kernel<<<NTOK0 / 4, 256, 0, stream>>>(A, Bb, sS, n1g + 256, aw1, ab1, aw2, ab2,
                                                    0, 1, nullptr, nullptr, NTOK0);
    topk_kernel<<<BB, 1024, 0, stream>>>(sS, selpos);
    scatter_kernel<<<dim3(GCH, BB), 256, 0, stream>>>(Bb, sS, selpos, A, part);
    extra_kernel<<<BB, 256, 0, stream>>>(part, A);
    rmsnorm_kernel<<<NTOK1 / 4, 256, 0, stream>>>(A, Bb, n2g + 256, NTOK1);
    gate_kernel<<<(NTOK1 + 255) / 256, 256, 0, stream>>>(Bb, gw, gb, tval, buckets, counts, imp,
                                                         NTOK1);
    ffn_kernel<<<dim3((NTOK1 + 31) / 32, 4), 512, 0, stream>>>(Bb, w1t, eb1, w2t, eb2, tval,
                                                               buckets, counts, CD, NTOK1);
    moe_add_kernel<<<NTOK1 / 4, 256, 0, stream>>>(CD, A, mg, NTOK1);
    pw_mfma<<<dim3((N1 + 31) / 32, BB), 256, 0, stream>>>(Bb, bth + 8192, btl + 8192,
                                                          mph + 8192, mpl + 8192,
                                                          bng + 128, bnb + 128, XB, CD, N1);
    conv_mfma<<<dim3((N1 + 127) / 128, BB), 256, 0, stream>>>(XB, cwh + 68608, cwl + 68608,
                                                              bng + 128, bnb + 128, CD, N1);
    proj_mfma<<<NTOK1 / 64, 256, 0, stream>>>(CD, pjwb + 32768, pjb + 256, A, NTOK1);
    endhead_kernel<<<NTOK1 / 4, 256, 0, stream>>>(A, aw1, ab1, aw2, ab2, hw, hb, ctb, NTOK1);
    finalsum_kernel<<<BB, 256, 0, stream>>>(ctb, imp, out);
}